// Round 1
// baseline (4906.954 us; speedup 1.0000x reference)
//
#include <hip/hip_runtime.h>

// MeshGraphNet-style rollout, fp32 baseline.
// N=20000 nodes, E=320000 edges, ROLL=2, MP=2.
// Pipeline per roll: node-enc MLP+BN, edge-enc MLP+BN, 2x[ge MLP+BN -> scatter -> gn MLP+BN+res],
// decoder, integrate, pd/history update. Then loss reduction.

constexpr int NN = 20000;
constexpr int NE = 320000;
constexpr int CHUNK = 80000;          // NE/4 : chunk the E x 128 intermediate
constexpr int NCHUNK = NE / CHUNK;

__device__ __forceinline__ float act_elu(float x) { return x > 0.f ? x : expm1f(x); }

// ---------------------------------------------------------------------------
// Generic tiled GEMM: out = ACT(X @ W + b), X:(M,K), W:(K,C) row-major.
// MODE 0: plain X (ld = K)
// MODE 1: edge gather: x(e,k) = k<128 ? ln[s0[e]][k] : k<256 ? ln[s1[e]][k-128] : le[e][k-256]
// MODE 2: node concat: x(n,k) = k<128 ? ln[n][k] : agg[n][k-128]
// STATS: accumulate per-channel sum/sumsq into stat[0..C) / stat[C..2C) (global atomics).
// Thread block: 256 threads, each thread computes 4 rows x TN cols.
template<int K, int C, int TN, int ACT, bool STATS, int MODE>
__global__ __launch_bounds__(256) void gemm_k(
    const float* __restrict__ X, const float* __restrict__ X2,
    const int* __restrict__ ep,
    const float* __restrict__ W, const float* __restrict__ bias,
    float* __restrict__ out, int M, float* __restrict__ stat)
{
  constexpr int COLT = C / TN;
  constexpr int ROWT = 256 / COLT;
  constexpr int BM = ROWT * 4;
  constexpr int BK = 32;
  static_assert(COLT * ROWT == 256, "bad cfg");
  static_assert(C % TN == 0 && TN % 4 == 0, "bad cfg");

  __shared__ float Xs[BK][BM];
  __shared__ float Ws[BK][C];
  __shared__ float red[2][C];

  const int tid = threadIdx.x;
  const int ct = tid % COLT, rt = tid / COLT;
  const int c0 = ct * TN;
  const int r0 = rt * 4;
  const int row0 = blockIdx.x * BM;

  float acc[4][TN];
#pragma unroll
  for (int i = 0; i < 4; ++i)
#pragma unroll
    for (int j = 0; j < TN; ++j) acc[i][j] = 0.f;

  for (int k0 = 0; k0 < K; k0 += BK) {
    const int kb = (K - k0 < BK) ? (K - k0) : BK;
    // stage W tile
    for (int i = tid; i < kb * C; i += 256) {
      int kk = i / C, c = i - kk * C;
      Ws[kk][c] = W[(size_t)(k0 + kk) * C + c];
    }
    // stage X tile (transposed: Xs[k][m])
    for (int i = tid; i < BM * kb; i += 256) {
      int m = i / kb, kk = i - m * kb;
      int row = row0 + m;
      float v = 0.f;
      if (row < M) {
        int k = k0 + kk;
        if constexpr (MODE == 0) {
          v = X[(size_t)row * K + k];
        } else if constexpr (MODE == 1) {
          if (k < 128)      v = X[(size_t)ep[2 * row] * 128 + k];
          else if (k < 256) v = X[(size_t)ep[2 * row + 1] * 128 + (k - 128)];
          else              v = X2[(size_t)row * 32 + (k - 256)];
        } else {
          if (k < 128) v = X[(size_t)row * 128 + k];
          else         v = X2[(size_t)row * 32 + (k - 128)];
        }
      }
      Xs[kk][m] = v;
    }
    __syncthreads();

    auto step = [&](int kk) {
      float4 xv = *(const float4*)&Xs[kk][r0];
      float xr[4] = {xv.x, xv.y, xv.z, xv.w};
#pragma unroll
      for (int j4 = 0; j4 < TN; j4 += 4) {
        float4 wv = *(const float4*)&Ws[kk][c0 + j4];
#pragma unroll
        for (int i = 0; i < 4; ++i) {
          acc[i][j4 + 0] = fmaf(xr[i], wv.x, acc[i][j4 + 0]);
          acc[i][j4 + 1] = fmaf(xr[i], wv.y, acc[i][j4 + 1]);
          acc[i][j4 + 2] = fmaf(xr[i], wv.z, acc[i][j4 + 2]);
          acc[i][j4 + 3] = fmaf(xr[i], wv.w, acc[i][j4 + 3]);
        }
      }
    };
    if (kb == BK) {
#pragma unroll 8
      for (int kk = 0; kk < BK; ++kk) step(kk);
    } else {
      for (int kk = 0; kk < kb; ++kk) step(kk);
    }
    __syncthreads();
  }

  // epilogue: bias + activation + store (+ per-channel stats)
  float psum[TN], psq[TN];
#pragma unroll
  for (int j = 0; j < TN; ++j) { psum[j] = 0.f; psq[j] = 0.f; }
  float bl[TN];
#pragma unroll
  for (int j = 0; j < TN; ++j) bl[j] = bias[c0 + j];

#pragma unroll
  for (int i = 0; i < 4; ++i) {
    int row = row0 + r0 + i;
    if (row < M) {
#pragma unroll
      for (int j = 0; j < TN; ++j) {
        float v = acc[i][j] + bl[j];
        if (ACT == 1) v = act_elu(v);
        else if (ACT == 2) v = tanhf(v);
        acc[i][j] = v;
        if (STATS) { psum[j] += v; psq[j] += v * v; }
      }
#pragma unroll
      for (int j4 = 0; j4 < TN; j4 += 4) {
        *(float4*)&out[(size_t)row * C + c0 + j4] =
            make_float4(acc[i][j4], acc[i][j4 + 1], acc[i][j4 + 2], acc[i][j4 + 3]);
      }
    }
  }

  if (STATS) {
    if (tid < C) { red[0][tid] = 0.f; red[1][tid] = 0.f; }
    __syncthreads();
#pragma unroll
    for (int j = 0; j < TN; ++j) {
      atomicAdd(&red[0][c0 + j], psum[j]);
      atomicAdd(&red[1][c0 + j], psq[j]);
    }
    __syncthreads();
    if (tid < C) {
      atomicAdd(&stat[tid], red[0][tid]);
      atomicAdd(&stat[C + tid], red[1][tid]);
    }
  }
}

// mu/var -> scale/shift for the normalize pass
__global__ void stats_fin_k(const float* __restrict__ stat, float invM,
                            const float* __restrict__ g, const float* __restrict__ be,
                            float* __restrict__ scl, float* __restrict__ shf, int C)
{
  int c = threadIdx.x;
  if (c < C) {
    float mu = stat[c] * invM;
    float var = stat[C + c] * invM - mu * mu;
    float rs = rsqrtf(var + 1e-5f);
    float s = rs * g[c];
    scl[c] = s;
    shf[c] = be[c] - mu * s;
  }
}

// out = h*scale + shift  (+ out if RES) -- float4 vectorized
template<int C, bool RES>
__global__ __launch_bounds__(256) void norm_k(const float* __restrict__ h,
    const float* __restrict__ scl, const float* __restrict__ shf,
    float* __restrict__ out, int total4)
{
  int i = blockIdx.x * blockDim.x + threadIdx.x;
  if (i >= total4) return;
  int c4 = (i % (C / 4)) * 4;
  float4 v = ((const float4*)h)[i];
  float4 s = *(const float4*)&scl[c4];
  float4 b = *(const float4*)&shf[c4];
  float4 o = make_float4(fmaf(v.x, s.x, b.x), fmaf(v.y, s.y, b.y),
                         fmaf(v.z, s.z, b.z), fmaf(v.w, s.w, b.w));
  if (RES) {
    float4 p = ((const float4*)out)[i];
    o.x += p.x; o.y += p.y; o.z += p.z; o.w += p.w;
  }
  ((float4*)out)[i] = o;
}

// agg[s0[e]] += ne[e]; agg[s1[e]] += ne[e]; le[e] += ne[e]
__global__ __launch_bounds__(256) void scatter_k(const float4* __restrict__ ne4,
    const int* __restrict__ ep, float* __restrict__ agg, float4* __restrict__ le4, int E8)
{
  int i = blockIdx.x * blockDim.x + threadIdx.x;
  if (i >= E8) return;
  int e = i >> 3, j = i & 7;
  float4 v = ne4[i];
  float4 l = le4[i];
  l.x += v.x; l.y += v.y; l.z += v.z; l.w += v.w;
  le4[i] = l;
  int b0 = ep[2 * e] * 32 + j * 4;
  int b1 = ep[2 * e + 1] * 32 + j * 4;
  atomicAdd(&agg[b0 + 0], v.x); atomicAdd(&agg[b0 + 1], v.y);
  atomicAdd(&agg[b0 + 2], v.z); atomicAdd(&agg[b0 + 3], v.w);
  atomicAdd(&agg[b1 + 0], v.x); atomicAdd(&agg[b1 + 1], v.y);
  atomicAdd(&agg[b1 + 2], v.z); atomicAdd(&agg[b1 + 3], v.w);
}

// decoder layer 2 (128->2) fused with pos/vel integration + preds write
__global__ __launch_bounds__(256) void dec2_int_k(const float* __restrict__ T,
    const float* __restrict__ W2, const float* __restrict__ b2,
    float* __restrict__ pos, float* __restrict__ vel, float* __restrict__ preds, int M)
{
  __shared__ float Wl[256];
  Wl[threadIdx.x] = W2[threadIdx.x];
  __syncthreads();
  int row = blockIdx.x * blockDim.x + threadIdx.x;
  if (row >= M) return;
  float ax = b2[0], ay = b2[1];
  const float4* t4 = (const float4*)(T + (size_t)row * 128);
#pragma unroll
  for (int k4 = 0; k4 < 32; ++k4) {
    float4 v = t4[k4];
    int k = k4 * 8;
    ax = fmaf(v.x, Wl[k + 0], ax); ay = fmaf(v.x, Wl[k + 1], ay);
    ax = fmaf(v.y, Wl[k + 2], ax); ay = fmaf(v.y, Wl[k + 3], ay);
    ax = fmaf(v.z, Wl[k + 4], ax); ay = fmaf(v.z, Wl[k + 5], ay);
    ax = fmaf(v.w, Wl[k + 6], ax); ay = fmaf(v.w, Wl[k + 7], ay);
  }
  float2 p = ((float2*)pos)[row], vv = ((float2*)vel)[row];
  p.x += ax; p.y += ay; vv.x += ax; vv.y += ay;
  ((float2*)pos)[row] = p; ((float2*)vel)[row] = vv;
  ((float2*)preds)[row] = p;
}

// edge_feat channels 4,5 = |pos[s0]-pos[s1]|
__global__ __launch_bounds__(256) void pd_upd_k(const float* __restrict__ pos,
    const int* __restrict__ ep, float* __restrict__ ef, int E)
{
  int e = blockIdx.x * blockDim.x + threadIdx.x;
  if (e >= E) return;
  float2 p0 = ((const float2*)pos)[ep[2 * e]];
  float2 p1 = ((const float2*)pos)[ep[2 * e + 1]];
  ef[(size_t)e * 6 + 4] = fabsf(p0.x - p1.x);
  ef[(size_t)e * 6 + 5] = fabsf(p0.y - p1.y);
}

// history: drop oldest timestep, append [pos, vel]
__global__ __launch_bounds__(256) void hist_shift_k(float* __restrict__ hist,
    const float* __restrict__ pos, const float* __restrict__ vel, int M)
{
  int n = blockIdx.x * blockDim.x + threadIdx.x;
  if (n >= M) return;
  float4* h4 = (float4*)(hist + (size_t)n * 40);
  float4 tmp[10];
#pragma unroll
  for (int t = 0; t < 10; ++t) tmp[t] = h4[t];
#pragma unroll
  for (int t = 0; t < 9; ++t) h4[t] = tmp[t + 1];
  float2 p = ((const float2*)pos)[n], v = ((const float2*)vel)[n];
  h4[9] = make_float4(p.x, p.y, v.x, v.y);
}

// build history (N,40), cur_pos/cur_vel, gt_future -> out
__global__ __launch_bounds__(256) void init_nodes_k(const float4* __restrict__ nodes4,
    float* __restrict__ hist, float* __restrict__ pos, float* __restrict__ vel,
    float* __restrict__ outGt, int M)
{
  int n = blockIdx.x * blockDim.x + threadIdx.x;
  if (n >= M) return;
  float4* h4 = (float4*)(hist + (size_t)n * 40);
  float4 v;
#pragma unroll
  for (int t = 0; t < 10; ++t) { v = nodes4[(size_t)t * M + n]; h4[t] = v; }
  ((float2*)pos)[n] = make_float2(v.x, v.y);   // t=9 pos
  ((float2*)vel)[n] = make_float2(v.z, v.w);   // t=9 vel
  float4 g0 = nodes4[(size_t)10 * M + n];
  float4 g1 = nodes4[(size_t)11 * M + n];
  float2* gt2 = (float2*)outGt;                // 8B-aligned (offset 80002 floats)
  gt2[(size_t)2 * n + 0] = make_float2(g0.x, g0.y);
  gt2[(size_t)2 * n + 1] = make_float2(g0.z, g0.w);
  gt2[(size_t)2 * (M + n) + 0] = make_float2(g1.x, g1.y);
  gt2[(size_t)2 * (M + n) + 1] = make_float2(g1.z, g1.w);
}

// edge_feat init: [attr0, attr1, |w10[s0]-w10[s1]| (4ch)]
__global__ __launch_bounds__(256) void init_edges_k(const float4* __restrict__ nodes4,
    const float* __restrict__ attr, const int* __restrict__ ep, float* __restrict__ ef, int E)
{
  int e = blockIdx.x * blockDim.x + threadIdx.x;
  if (e >= E) return;
  float4 w0 = nodes4[(size_t)10 * NN + ep[2 * e]];
  float4 w1 = nodes4[(size_t)10 * NN + ep[2 * e + 1]];
  float2 a = ((const float2*)attr)[e];
  float* o = ef + (size_t)e * 6;
  o[0] = a.x; o[1] = a.y;
  o[2] = fabsf(w0.x - w1.x); o[3] = fabsf(w0.y - w1.y);
  o[4] = fabsf(w0.z - w1.z); o[5] = fabsf(w0.w - w1.w);
}

__global__ __launch_bounds__(256) void loss_k(const float* __restrict__ preds,
    const float* __restrict__ gtf, float* __restrict__ acc)
{
  int i = blockIdx.x * blockDim.x + threadIdx.x;
  float d2 = 0.f;
  if (i < 2 * NN * 2) {
    int r = i / (NN * 2);
    int rem = i - r * (NN * 2);
    int n = rem >> 1, c = rem & 1;
    float df = preds[i] - gtf[((size_t)r * NN + n) * 4 + c];
    d2 = df * df;
  }
#pragma unroll
  for (int o = 32; o > 0; o >>= 1) d2 += __shfl_down(d2, o, 64);
  __shared__ float sb[4];
  int lane = threadIdx.x & 63, w = threadIdx.x >> 6;
  if (lane == 0) sb[w] = d2;
  __syncthreads();
  if (threadIdx.x == 0) atomicAdd(acc, sb[0] + sb[1] + sb[2] + sb[3]);
}

__global__ void loss_write_k(const float* __restrict__ acc, float* __restrict__ o)
{
  float s = *acc;
  o[0] = s * 0.25f;            // sum(d^2)/(2*5e-5)/(ROLL*N) = sum * 1e4/4e4
  o[1] = s * (1.f / 80000.f);  // mean
}

extern "C" void kernel_launch(void* const* d_in, const int* in_sizes, int n_in,
                              void* d_out, int out_size, void* d_ws, size_t ws_size,
                              hipStream_t stream)
{
  (void)in_sizes; (void)n_in; (void)out_size; (void)ws_size;
  const float* nodes = (const float*)d_in[0];
  const int*   ep    = (const int*)d_in[1];
  const float* eattr = (const float*)d_in[2];
  const float *en_W1 = (const float*)d_in[3],  *en_b1 = (const float*)d_in[4],
              *en_W2 = (const float*)d_in[5],  *en_b2 = (const float*)d_in[6],
              *en_g  = (const float*)d_in[7],  *en_be = (const float*)d_in[8];
  const float *ee_W1 = (const float*)d_in[9],  *ee_b1 = (const float*)d_in[10],
              *ee_W2 = (const float*)d_in[11], *ee_b2 = (const float*)d_in[12],
              *ee_g  = (const float*)d_in[13], *ee_be = (const float*)d_in[14];
  const float *ge_W1 = (const float*)d_in[15], *ge_b1 = (const float*)d_in[16],
              *ge_W2 = (const float*)d_in[17], *ge_b2 = (const float*)d_in[18],
              *ge_g  = (const float*)d_in[19], *ge_be = (const float*)d_in[20];
  const float *gn_W1 = (const float*)d_in[21], *gn_b1 = (const float*)d_in[22],
              *gn_W2 = (const float*)d_in[23], *gn_b2 = (const float*)d_in[24],
              *gn_g  = (const float*)d_in[25], *gn_be = (const float*)d_in[26];
  const float *d_W1  = (const float*)d_in[27], *d_b1  = (const float*)d_in[28],
              *d_W2  = (const float*)d_in[29], *d_b2  = (const float*)d_in[30];

  float* out = (float*)d_out;
  float* outPreds = out;           // (1,2,N,2) = 80000
  float* outLoss  = out + 80000;   // 2 scalars
  float* outGt    = out + 80002;   // (2,N,4) = 160000

  float* ws = (float*)d_ws;
  size_t off = 0;
  auto alloc = [&](size_t nf) { float* p = ws + off; off += (nf + 15) & ~(size_t)15; return p; };
  float* hist = alloc((size_t)NN * 40);
  float* ef   = alloc((size_t)NE * 6);
  float* ln   = alloc((size_t)NN * 128);
  float* le   = alloc((size_t)NE * 32);
  float* ne   = alloc((size_t)NE * 32);
  float* agg  = alloc((size_t)NN * 32);
  float* pos  = alloc((size_t)NN * 2);
  float* vel  = alloc((size_t)NN * 2);
  float* bufA = alloc((size_t)CHUNK * 128);  // also h1n(N*128), h1e(E*32), hgn1(N*256), dect(N*128)
  float* bufB = alloc((size_t)NE * 32);      // h2n, h2e, hge2, hgn2
  float* stat = alloc(512);
  float* scl  = alloc(256);
  float* shf  = alloc(256);
  float* lacc = alloc(16);

  const int GN64 = (NN + 63) / 64;      // 313
  const int GN32 = (NN + 31) / 32;      // 625 (exact)
  const int GE128 = NE / 128;           // 2500
  const int GNORM_N = (NN * 32 + 255) / 256;   // NN*128/4 elems
  const int GNORM_E = (NE * 8 + 255) / 256;    // NE*32/4 elems

  init_nodes_k<<<(NN + 255) / 256, 256, 0, stream>>>((const float4*)nodes, hist, pos, vel, outGt, NN);
  init_edges_k<<<(NE + 255) / 256, 256, 0, stream>>>((const float4*)nodes, eattr, ep, ef, NE);

  for (int r = 0; r < 2; ++r) {
    // ---- node encoder: hist(N,40) -> ln(N,128) ----
    hipMemsetAsync(stat, 0, 2 * 128 * sizeof(float), stream);
    gemm_k<40, 128, 8, 1, false, 0><<<GN64, 256, 0, stream>>>(hist, nullptr, nullptr, en_W1, en_b1, bufA, NN, nullptr);
    gemm_k<128, 128, 8, 1, true, 0><<<GN64, 256, 0, stream>>>(bufA, nullptr, nullptr, en_W2, en_b2, bufB, NN, stat);
    stats_fin_k<<<1, 256, 0, stream>>>(stat, 1.f / NN, en_g, en_be, scl, shf, 128);
    norm_k<128, false><<<GNORM_N, 256, 0, stream>>>(bufB, scl, shf, ln, NN * 32);

    // ---- edge encoder: ef(E,6) -> le(E,32) ----
    hipMemsetAsync(stat, 0, 2 * 32 * sizeof(float), stream);
    gemm_k<6, 32, 4, 1, false, 0><<<GE128, 256, 0, stream>>>(ef, nullptr, nullptr, ee_W1, ee_b1, bufA, NE, nullptr);
    gemm_k<32, 32, 4, 1, true, 0><<<GE128, 256, 0, stream>>>(bufA, nullptr, nullptr, ee_W2, ee_b2, bufB, NE, stat);
    stats_fin_k<<<1, 256, 0, stream>>>(stat, 1.f / NE, ee_g, ee_be, scl, shf, 32);
    norm_k<32, false><<<GNORM_E, 256, 0, stream>>>(bufB, scl, shf, le, NE * 8);

    for (int mp = 0; mp < 2; ++mp) {
      // ---- ge MLP: gather(ln[s0],ln[s1],le)(E,288) -> ne(E,32) ----
      hipMemsetAsync(stat, 0, 2 * 32 * sizeof(float), stream);
      for (int c = 0; c < NCHUNK; ++c) {
        const size_t co = (size_t)c * CHUNK;
        gemm_k<288, 128, 8, 1, false, 1><<<CHUNK / 64, 256, 0, stream>>>(
            ln, le + co * 32, ep + co * 2, ge_W1, ge_b1, bufA, CHUNK, nullptr);
        gemm_k<128, 32, 4, 1, true, 0><<<CHUNK / 128, 256, 0, stream>>>(
            bufA, nullptr, nullptr, ge_W2, ge_b2, bufB + co * 32, CHUNK, stat);
      }
      stats_fin_k<<<1, 256, 0, stream>>>(stat, 1.f / NE, ge_g, ge_be, scl, shf, 32);
      norm_k<32, false><<<GNORM_E, 256, 0, stream>>>(bufB, scl, shf, ne, NE * 8);

      // ---- scatter: agg = sum_e ne -> s0,s1 ; le += ne ----
      hipMemsetAsync(agg, 0, (size_t)NN * 32 * sizeof(float), stream);
      scatter_k<<<GNORM_E, 256, 0, stream>>>((const float4*)ne, ep, agg, (float4*)le, NE * 8);

      // ---- gn MLP: concat(ln,agg)(N,160) -> +ln(N,128) ----
      hipMemsetAsync(stat, 0, 2 * 128 * sizeof(float), stream);
      gemm_k<160, 256, 8, 1, false, 2><<<GN32, 256, 0, stream>>>(ln, agg, nullptr, gn_W1, gn_b1, bufA, NN, nullptr);
      gemm_k<256, 128, 8, 1, true, 0><<<GN64, 256, 0, stream>>>(bufA, nullptr, nullptr, gn_W2, gn_b2, bufB, NN, stat);
      stats_fin_k<<<1, 256, 0, stream>>>(stat, 1.f / NN, gn_g, gn_be, scl, shf, 128);
      norm_k<128, true><<<GNORM_N, 256, 0, stream>>>(bufB, scl, shf, ln, NN * 32);
    }

    // ---- decoder + integrate ----
    gemm_k<128, 128, 8, 2, false, 0><<<GN64, 256, 0, stream>>>(ln, nullptr, nullptr, d_W1, d_b1, bufA, NN, nullptr);
    dec2_int_k<<<(NN + 255) / 256, 256, 0, stream>>>(bufA, d_W2, d_b2, pos, vel, outPreds + (size_t)r * NN * 2, NN);

    if (r == 0) {  // last-roll updates don't affect outputs
      pd_upd_k<<<(NE + 255) / 256, 256, 0, stream>>>(pos, ep, ef, NE);
      hist_shift_k<<<(NN + 255) / 256, 256, 0, stream>>>(hist, pos, vel, NN);
    }
  }

  // ---- losses ----
  hipMemsetAsync(lacc, 0, sizeof(float), stream);
  loss_k<<<(2 * NN * 2 + 255) / 256, 256, 0, stream>>>(outPreds, outGt, lacc);
  loss_write_k<<<1, 1, 0, stream>>>(lacc, outLoss);
}

// Round 2
// 1940.388 us; speedup vs baseline: 2.5289x; 2.5289x over previous
//
#include <hip/hip_runtime.h>

// MeshGraphNet rollout, round 2: bf16-MFMA GEMMs + CSR gather aggregation.
// N=20000 nodes, E=320000 edges, ROLL=2, MP=2.

constexpr int NN = 20000;
constexpr int NE = 320000;
constexpr int CH = 160000;   // ge chunk (E/2) to bound the E x 128 bf16 intermediate

typedef __attribute__((ext_vector_type(8))) short short8;
typedef __attribute__((ext_vector_type(4))) float f32x4;

__device__ __forceinline__ float act_elu(float x) { return x > 0.f ? x : expm1f(x); }
__device__ __forceinline__ unsigned short f2bf(float f) {
  unsigned u = __builtin_bit_cast(unsigned, f);
  return (unsigned short)((u + 0x7FFFu + ((u >> 16) & 1u)) >> 16);
}
__device__ __forceinline__ float bf2f(unsigned short h) {
  unsigned u = ((unsigned)h) << 16; return __builtin_bit_cast(float, u);
}

// ---------------------------------------------------------------------------
// bf16 MFMA GEMM: out(M,C) = ACT(X(M,K) @ W(K,C) + b), bf16 in/out, f32 acc.
// Wt = W^T as bf16 (C,K). 256 threads = 4 waves (NWM x NWC), tile BM x C.
// MODE 0: A is (M,K) bf16.
// MODE 1: edge gather: x(e,k) = k<128 ? A[ep[2e]*128+k] : k<256 ? A[ep[2e+1]*128+k-128] : A2[e*32+k-256]
// MODE 2: node concat: x(n,k) = k<128 ? A[n*128+k] : A2[n*32+k-128]
// STATS: per-channel sum/sumsq of activated outputs -> stat[0..C),stat[C..2C).
template<int K, int C, int BM, int NWM, int NWC, int ACT, bool STATS, int MODE>
__global__ __launch_bounds__(256) void mgemm_k(
    const unsigned short* __restrict__ A, const unsigned short* __restrict__ A2,
    const int* __restrict__ ep,
    const unsigned short* __restrict__ Wt, const float* __restrict__ bias,
    unsigned short* __restrict__ out, int M, float* __restrict__ stat)
{
  constexpr int FM = BM / (16 * NWM);
  constexpr int FC = C / (16 * NWC);
  constexpr int NKS = (K + 31) / 32;
  constexpr int RB = 40;                       // padded LDS row (32 bf16 + 8 pad) = 80B
  static_assert(NWM * NWC == 4, "4 waves");

  __shared__ unsigned short As[BM * RB];
  __shared__ unsigned short Bs[C * RB];
  __shared__ float red[2][C];
  __shared__ int eps[(MODE == 1) ? BM * 2 : 2];

  const int tid = threadIdx.x;
  const int row0 = blockIdx.x * BM;
  const int wave = tid >> 6, lane = tid & 63;
  const int wm = wave % NWM, wc = wave / NWM;
  const int lr = lane & 15, kg = lane >> 4;

  if (MODE == 1) {
    for (int i = tid; i < BM * 2; i += 256) eps[i] = ep[row0 * 2 + i];
    __syncthreads();
  }

  f32x4 acc[FM][FC];
#pragma unroll
  for (int i = 0; i < FM; ++i)
#pragma unroll
    for (int j = 0; j < FC; ++j) acc[i][j] = (f32x4){0.f, 0.f, 0.f, 0.f};

  for (int ks = 0; ks < NKS; ++ks) {
    const int k0 = ks * 32;
    for (int idx = tid; idx < (BM + C) * 4; idx += 256) {
      uint4 v = make_uint4(0, 0, 0, 0);
      if (idx < BM * 4) {
        int m = idx >> 2, chk = idx & 3;
        int kglob = k0 + chk * 8;
        const unsigned short* src = nullptr;
        if (MODE == 0) {
          int row = row0 + m;
          if (row < M && kglob + 8 <= K) src = A + (size_t)row * K + kglob;
        } else if (MODE == 1) {
          int e = row0 + m;
          if (kglob < 128)      src = A + (size_t)eps[2 * m] * 128 + kglob;
          else if (kglob < 256) src = A + (size_t)eps[2 * m + 1] * 128 + (kglob - 128);
          else                  src = A2 + (size_t)e * 32 + (kglob - 256);
        } else {
          int row = row0 + m;
          if (row < M) {
            if (kglob < 128) src = A + (size_t)row * 128 + kglob;
            else             src = A2 + (size_t)row * 32 + (kglob - 128);
          }
        }
        if (src) v = *(const uint4*)src;
        *(uint4*)&As[m * RB + chk * 8] = v;
      } else {
        int i2 = idx - BM * 4;
        int c = i2 >> 2, chk = i2 & 3;
        int kglob = k0 + chk * 8;
        if (kglob + 8 <= K) v = *(const uint4*)&Wt[(size_t)c * K + kglob];
        *(uint4*)&Bs[c * RB + chk * 8] = v;
      }
    }
    __syncthreads();

    short8 af[FM], bfr[FC];
#pragma unroll
    for (int i = 0; i < FM; ++i) {
      int r = (wm * FM + i) * 16 + lr;
      af[i] = __builtin_bit_cast(short8, *(const uint4*)&As[r * RB + kg * 8]);
    }
#pragma unroll
    for (int j = 0; j < FC; ++j) {
      int c = (wc * FC + j) * 16 + lr;
      bfr[j] = __builtin_bit_cast(short8, *(const uint4*)&Bs[c * RB + kg * 8]);
    }
#pragma unroll
    for (int i = 0; i < FM; ++i)
#pragma unroll
      for (int j = 0; j < FC; ++j)
        acc[i][j] = __builtin_amdgcn_mfma_f32_16x16x32_bf16(af[i], bfr[j], acc[i][j], 0, 0, 0);
    __syncthreads();
  }

  // epilogue: bias + activation + bf16 store (+ stats)
  float psum[FC], psq[FC], bl[FC];
#pragma unroll
  for (int j = 0; j < FC; ++j) {
    psum[j] = 0.f; psq[j] = 0.f;
    bl[j] = bias[(wc * FC + j) * 16 + lr];
  }
#pragma unroll
  for (int i = 0; i < FM; ++i) {
#pragma unroll
    for (int t = 0; t < 4; ++t) {
      int row = row0 + (wm * FM + i) * 16 + kg * 4 + t;
      bool ok = row < M;
#pragma unroll
      for (int j = 0; j < FC; ++j) {
        float v = acc[i][j][t] + bl[j];
        if (ACT == 1) v = act_elu(v);
        else if (ACT == 2) v = tanhf(v);
        if (ok) {
          out[(size_t)row * C + (wc * FC + j) * 16 + lr] = f2bf(v);
          if (STATS) { psum[j] += v; psq[j] += v * v; }
        }
      }
    }
  }

  if (STATS) {
    for (int i = tid; i < 2 * C; i += 256) ((float*)red)[i] = 0.f;
    __syncthreads();
#pragma unroll
    for (int j = 0; j < FC; ++j) {
      int c = (wc * FC + j) * 16 + lr;
      atomicAdd(&red[0][c], psum[j]);
      atomicAdd(&red[1][c], psq[j]);
    }
    __syncthreads();
    for (int i = tid; i < C; i += 256) {
      atomicAdd(&stat[i], red[0][i]);
      atomicAdd(&stat[C + i], red[1][i]);
    }
  }
}

// W(K,C) f32 -> Wt(C,K) bf16
__global__ __launch_bounds__(256) void wtrans_k(const float* __restrict__ W,
    unsigned short* __restrict__ Wt, int K, int C)
{
  int i = blockIdx.x * 256 + threadIdx.x;
  if (i < K * C) {
    int k = i / C, c = i - k * C;
    Wt[(size_t)c * K + k] = f2bf(W[i]);
  }
}

__global__ void stats_fin_k(const float* __restrict__ stat, float invM,
                            const float* __restrict__ g, const float* __restrict__ be,
                            float* __restrict__ scl, float* __restrict__ shf, int C)
{
  int c = threadIdx.x;
  if (c < C) {
    float mu = stat[c] * invM;
    float var = stat[C + c] * invM - mu * mu;
    float rs = rsqrtf(var + 1e-5f);
    float s = rs * g[c];
    scl[c] = s;
    shf[c] = be[c] - mu * s;
  }
}

// out(f32) = h(bf16)*scl + shf (+ out if RES); also writes bf16 mirror.
template<int C, bool RES>
__global__ __launch_bounds__(256) void normb_k(const unsigned short* __restrict__ h,
    const float* __restrict__ scl, const float* __restrict__ shf,
    float* __restrict__ out, unsigned short* __restrict__ out_bf, int total8)
{
  int i = blockIdx.x * 256 + threadIdx.x;
  if (i >= total8) return;
  int c8 = (i % (C / 8)) * 8;
  uint4 hv = ((const uint4*)h)[i];
  const unsigned short* hp = (const unsigned short*)&hv;
  float f[8];
#pragma unroll
  for (int j = 0; j < 8; ++j) f[j] = fmaf(bf2f(hp[j]), scl[c8 + j], shf[c8 + j]);
  if (RES) {
    float4 p0 = ((const float4*)out)[2 * i], p1 = ((const float4*)out)[2 * i + 1];
    f[0] += p0.x; f[1] += p0.y; f[2] += p0.z; f[3] += p0.w;
    f[4] += p1.x; f[5] += p1.y; f[6] += p1.z; f[7] += p1.w;
  }
  ((float4*)out)[2 * i]     = make_float4(f[0], f[1], f[2], f[3]);
  ((float4*)out)[2 * i + 1] = make_float4(f[4], f[5], f[6], f[7]);
  uint4 o;
  unsigned short* op = (unsigned short*)&o;
#pragma unroll
  for (int j = 0; j < 8; ++j) op[j] = f2bf(f[j]);
  ((uint4*)out_bf)[i] = o;
}

// fused edge-encoder: ef(E,6) -> elu(.@W1+b1) -> elu(.@W2+b2) -> bf16 + stats
__global__ __launch_bounds__(256) void ee_fused_k(const float* __restrict__ ef,
    const float* __restrict__ W1, const float* __restrict__ b1,
    const float* __restrict__ W2, const float* __restrict__ b2,
    unsigned short* __restrict__ h2bf, float* __restrict__ stat, int E)
{
  __shared__ float sW1[6 * 32], sW2[32 * 32], sb1[32], sb2[32];
  __shared__ float red[2][33];
  int tid = threadIdx.x;
  for (int i = tid; i < 6 * 32; i += 256) sW1[i] = W1[i];
  for (int i = tid; i < 32 * 32; i += 256) sW2[i] = W2[i];
  if (tid < 32) { sb1[tid] = b1[tid]; sb2[tid] = b2[tid]; red[0][tid] = 0.f; red[1][tid] = 0.f; }
  __syncthreads();
  int e = blockIdx.x * 256 + tid;
  if (e < E) {
    float x[6];
#pragma unroll
    for (int k = 0; k < 6; ++k) x[k] = ef[(size_t)e * 6 + k];
    float h1[32];
#pragma unroll
    for (int c = 0; c < 32; ++c) {
      float v = sb1[c];
#pragma unroll
      for (int k = 0; k < 6; ++k) v = fmaf(x[k], sW1[k * 32 + c], v);
      h1[c] = act_elu(v);
    }
    uint4 ob[2][2];
    unsigned short* op = (unsigned short*)ob;
#pragma unroll
    for (int c = 0; c < 32; ++c) {
      float v = sb2[c];
#pragma unroll
      for (int k = 0; k < 32; ++k) v = fmaf(h1[k], sW2[k * 32 + c], v);
      v = act_elu(v);
      op[c] = f2bf(v);
      atomicAdd(&red[0][c], v);
      atomicAdd(&red[1][c], v * v);
    }
    uint4* dst = (uint4*)(h2bf + (size_t)e * 32);
    dst[0] = ob[0][0]; dst[1] = ob[0][1]; dst[2] = ob[1][0]; dst[3] = ob[1][1];
  }
  __syncthreads();
  if (tid < 32) {
    atomicAdd(&stat[tid], red[0][tid]);
    atomicAdd(&stat[32 + tid], red[1][tid]);
  }
}

// ---- CSR build ----
__global__ __launch_bounds__(256) void csr_count_k(const int* __restrict__ ep,
    int* __restrict__ deg, int E)
{
  int e = blockIdx.x * 256 + threadIdx.x;
  if (e < E) { atomicAdd(&deg[ep[2 * e]], 1); atomicAdd(&deg[ep[2 * e + 1]], 1); }
}

__global__ __launch_bounds__(1024) void csr_scan_k(const int* __restrict__ deg,
    int* __restrict__ off, int* __restrict__ cursor, int N)
{
  __shared__ int part[1024];
  int t = threadIdx.x;
  const int CHK = (N + 1023) / 1024;
  int c0 = t * CHK, c1 = min(c0 + CHK, N);
  int s = 0;
  for (int i = c0; i < c1; ++i) s += deg[i];
  part[t] = s;
  __syncthreads();
  for (int o = 1; o < 1024; o <<= 1) {
    int v = (t >= o) ? part[t - o] : 0;
    __syncthreads();
    part[t] += v;
    __syncthreads();
  }
  int run = t ? part[t - 1] : 0;
  for (int i = c0; i < c1; ++i) { int d = deg[i]; off[i] = run; cursor[i] = run; run += d; }
}

__global__ __launch_bounds__(256) void csr_fill_k(const int* __restrict__ ep,
    int* __restrict__ cursor, int* __restrict__ eidx, int E)
{
  int e = blockIdx.x * 256 + threadIdx.x;
  if (e < E) {
    int p0 = atomicAdd(&cursor[ep[2 * e]], 1); eidx[p0] = e;
    int p1 = atomicAdd(&cursor[ep[2 * e + 1]], 1); eidx[p1] = e;
  }
}

// agg_bf[n][c] = scl[c]*sum_e h2e[e][c] + deg[n]*shf[c]  (one wave per node)
__global__ __launch_bounds__(256) void gather_agg_k(const unsigned short* __restrict__ h2e,
    const float* __restrict__ scl, const float* __restrict__ shf,
    const int* __restrict__ off, const int* __restrict__ deg, const int* __restrict__ eidx,
    unsigned short* __restrict__ agg_bf, int N)
{
  int wid = (blockIdx.x * 256 + threadIdx.x) >> 6;
  if (wid >= N) return;
  int lane = threadIdx.x & 63;
  int c = lane & 31, half = lane >> 5;
  int o = off[wid], d = deg[wid];
  float s = 0.f;
  for (int i = half; i < d; i += 2) {
    int e = eidx[o + i];
    s += bf2f(h2e[(size_t)e * 32 + c]);
  }
  s += __shfl_down(s, 32, 64);
  if (half == 0) {
    float v = fmaf(scl[c], s, (float)d * shf[c]);
    agg_bf[(size_t)wid * 32 + c] = f2bf(v);
  }
}

// le(f32) += h2e*scl+shf ; refresh le bf16 mirror
__global__ __launch_bounds__(256) void le_upd_k(const unsigned short* __restrict__ h2e,
    const float* __restrict__ scl, const float* __restrict__ shf,
    float* __restrict__ le, unsigned short* __restrict__ le_bf, int total8)
{
  int i = blockIdx.x * 256 + threadIdx.x;
  if (i >= total8) return;
  int c8 = (i & 3) * 8;
  uint4 hv = ((const uint4*)h2e)[i];
  const unsigned short* hp = (const unsigned short*)&hv;
  float4 l0 = ((const float4*)le)[2 * i], l1 = ((const float4*)le)[2 * i + 1];
  float f[8] = {l0.x, l0.y, l0.z, l0.w, l1.x, l1.y, l1.z, l1.w};
#pragma unroll
  for (int j = 0; j < 8; ++j) f[j] += fmaf(bf2f(hp[j]), scl[c8 + j], shf[c8 + j]);
  ((float4*)le)[2 * i]     = make_float4(f[0], f[1], f[2], f[3]);
  ((float4*)le)[2 * i + 1] = make_float4(f[4], f[5], f[6], f[7]);
  uint4 o;
  unsigned short* op = (unsigned short*)&o;
#pragma unroll
  for (int j = 0; j < 8; ++j) op[j] = f2bf(f[j]);
  ((uint4*)le_bf)[i] = o;
}

// decoder layer2 (128->2, bf16 in) + integrate + preds
__global__ __launch_bounds__(256) void dec2i_k(const unsigned short* __restrict__ T,
    const float* __restrict__ W2, const float* __restrict__ b2,
    float* __restrict__ pos, float* __restrict__ vel, float* __restrict__ preds, int M)
{
  __shared__ float Wl[256];
  Wl[threadIdx.x] = W2[threadIdx.x];
  __syncthreads();
  int row = blockIdx.x * 256 + threadIdx.x;
  if (row >= M) return;
  float ax = b2[0], ay = b2[1];
  const uint4* t4 = (const uint4*)(T + (size_t)row * 128);
#pragma unroll
  for (int k8 = 0; k8 < 16; ++k8) {
    uint4 v = t4[k8];
    const unsigned short* p = (const unsigned short*)&v;
#pragma unroll
    for (int j = 0; j < 8; ++j) {
      float f = bf2f(p[j]);
      int k = k8 * 8 + j;
      ax = fmaf(f, Wl[2 * k], ax);
      ay = fmaf(f, Wl[2 * k + 1], ay);
    }
  }
  float2 p = ((float2*)pos)[row], vv = ((float2*)vel)[row];
  p.x += ax; p.y += ay; vv.x += ax; vv.y += ay;
  ((float2*)pos)[row] = p; ((float2*)vel)[row] = vv;
  ((float2*)preds)[row] = p;
}

__global__ __launch_bounds__(256) void pd_upd_k(const float* __restrict__ pos,
    const int* __restrict__ ep, float* __restrict__ ef, int E)
{
  int e = blockIdx.x * 256 + threadIdx.x;
  if (e >= E) return;
  float2 p0 = ((const float2*)pos)[ep[2 * e]];
  float2 p1 = ((const float2*)pos)[ep[2 * e + 1]];
  ef[(size_t)e * 6 + 4] = fabsf(p0.x - p1.x);
  ef[(size_t)e * 6 + 5] = fabsf(p0.y - p1.y);
}

__global__ __launch_bounds__(256) void hist_shift_k(float* __restrict__ hist,
    unsigned short* __restrict__ histb,
    const float* __restrict__ pos, const float* __restrict__ vel, int M)
{
  int n = blockIdx.x * 256 + threadIdx.x;
  if (n >= M) return;
  float4* h4 = (float4*)(hist + (size_t)n * 40);
  float4 tmp[10];
#pragma unroll
  for (int t = 0; t < 10; ++t) tmp[t] = h4[t];
  float2 pp = ((const float2*)pos)[n], vv = ((const float2*)vel)[n];
  tmp[0] = tmp[1];  // shift handled below by rewriting 0..9
  unsigned* hb = (unsigned*)(histb + (size_t)n * 40);
#pragma unroll
  for (int t = 0; t < 9; ++t) {
    float4 v = ((const float4*)&tmp[0])[0]; // placate compiler; real value below
    v = tmp[t + 1];
    h4[t] = v;
    hb[2 * t]     = (unsigned)f2bf(v.x) | ((unsigned)f2bf(v.y) << 16);
    hb[2 * t + 1] = (unsigned)f2bf(v.z) | ((unsigned)f2bf(v.w) << 16);
  }
  float4 nv = make_float4(pp.x, pp.y, vv.x, vv.y);
  h4[9] = nv;
  hb[18] = (unsigned)f2bf(nv.x) | ((unsigned)f2bf(nv.y) << 16);
  hb[19] = (unsigned)f2bf(nv.z) | ((unsigned)f2bf(nv.w) << 16);
}

__global__ __launch_bounds__(256) void init_nodes_k(const float4* __restrict__ nodes4,
    float* __restrict__ hist, unsigned short* __restrict__ histb,
    float* __restrict__ pos, float* __restrict__ vel,
    float* __restrict__ outGt, int M)
{
  int n = blockIdx.x * 256 + threadIdx.x;
  if (n >= M) return;
  float4* h4 = (float4*)(hist + (size_t)n * 40);
  unsigned* hb = (unsigned*)(histb + (size_t)n * 40);
  float4 v;
#pragma unroll
  for (int t = 0; t < 10; ++t) {
    v = nodes4[(size_t)t * M + n];
    h4[t] = v;
    hb[2 * t]     = (unsigned)f2bf(v.x) | ((unsigned)f2bf(v.y) << 16);
    hb[2 * t + 1] = (unsigned)f2bf(v.z) | ((unsigned)f2bf(v.w) << 16);
  }
  ((float2*)pos)[n] = make_float2(v.x, v.y);
  ((float2*)vel)[n] = make_float2(v.z, v.w);
  float4 g0 = nodes4[(size_t)10 * M + n];
  float4 g1 = nodes4[(size_t)11 * M + n];
  float2* gt2 = (float2*)outGt;
  gt2[(size_t)2 * n + 0] = make_float2(g0.x, g0.y);
  gt2[(size_t)2 * n + 1] = make_float2(g0.z, g0.w);
  gt2[(size_t)2 * (M + n) + 0] = make_float2(g1.x, g1.y);
  gt2[(size_t)2 * (M + n) + 1] = make_float2(g1.z, g1.w);
}

__global__ __launch_bounds__(256) void init_edges_k(const float4* __restrict__ nodes4,
    const float* __restrict__ attr, const int* __restrict__ ep, float* __restrict__ ef, int E)
{
  int e = blockIdx.x * 256 + threadIdx.x;
  if (e >= E) return;
  float4 w0 = nodes4[(size_t)10 * NN + ep[2 * e]];
  float4 w1 = nodes4[(size_t)10 * NN + ep[2 * e + 1]];
  float2 a = ((const float2*)attr)[e];
  float* o = ef + (size_t)e * 6;
  o[0] = a.x; o[1] = a.y;
  o[2] = fabsf(w0.x - w1.x); o[3] = fabsf(w0.y - w1.y);
  o[4] = fabsf(w0.z - w1.z); o[5] = fabsf(w0.w - w1.w);
}

__global__ __launch_bounds__(256) void loss_k(const float* __restrict__ preds,
    const float* __restrict__ gtf, float* __restrict__ acc)
{
  int i = blockIdx.x * 256 + threadIdx.x;
  float d2 = 0.f;
  if (i < 2 * NN * 2) {
    int r = i / (NN * 2);
    int rem = i - r * (NN * 2);
    int n = rem >> 1, c = rem & 1;
    float df = preds[i] - gtf[((size_t)r * NN + n) * 4 + c];
    d2 = df * df;
  }
#pragma unroll
  for (int o = 32; o > 0; o >>= 1) d2 += __shfl_down(d2, o, 64);
  __shared__ float sb[4];
  int lane = threadIdx.x & 63, w = threadIdx.x >> 6;
  if (lane == 0) sb[w] = d2;
  __syncthreads();
  if (threadIdx.x == 0) atomicAdd(acc, sb[0] + sb[1] + sb[2] + sb[3]);
}

__global__ void loss_write_k(const float* __restrict__ acc, float* __restrict__ o)
{
  float s = *acc;
  o[0] = s * 0.25f;
  o[1] = s * (1.f / 80000.f);
}

extern "C" void kernel_launch(void* const* d_in, const int* in_sizes, int n_in,
                              void* d_out, int out_size, void* d_ws, size_t ws_size,
                              hipStream_t stream)
{
  (void)in_sizes; (void)n_in; (void)out_size; (void)ws_size;
  const float* nodes = (const float*)d_in[0];
  const int*   ep    = (const int*)d_in[1];
  const float* eattr = (const float*)d_in[2];
  const float *en_W1 = (const float*)d_in[3],  *en_b1 = (const float*)d_in[4],
              *en_W2 = (const float*)d_in[5],  *en_b2 = (const float*)d_in[6],
              *en_g  = (const float*)d_in[7],  *en_be = (const float*)d_in[8];
  const float *ee_W1 = (const float*)d_in[9],  *ee_b1 = (const float*)d_in[10],
              *ee_W2 = (const float*)d_in[11], *ee_b2 = (const float*)d_in[12],
              *ee_g  = (const float*)d_in[13], *ee_be = (const float*)d_in[14];
  const float *ge_W1 = (const float*)d_in[15], *ge_b1 = (const float*)d_in[16],
              *ge_W2 = (const float*)d_in[17], *ge_b2 = (const float*)d_in[18],
              *ge_g  = (const float*)d_in[19], *ge_be = (const float*)d_in[20];
  const float *gn_W1 = (const float*)d_in[21], *gn_b1 = (const float*)d_in[22],
              *gn_W2 = (const float*)d_in[23], *gn_b2 = (const float*)d_in[24],
              *gn_g  = (const float*)d_in[25], *gn_be = (const float*)d_in[26];
  const float *d_W1  = (const float*)d_in[27], *d_b1  = (const float*)d_in[28],
              *d_W2  = (const float*)d_in[29], *d_b2  = (const float*)d_in[30];

  float* out = (float*)d_out;
  float* outPreds = out;
  float* outLoss  = out + 80000;
  float* outGt    = out + 80002;

  float* ws = (float*)d_ws;
  size_t off = 0;
  auto alloc = [&](size_t nf) { float* p = ws + off; off += (nf + 15) & ~(size_t)15; return p; };
  float* hist  = alloc((size_t)NN * 40);
  unsigned short* histb = (unsigned short*)alloc((size_t)NN * 20);
  float* ef    = alloc((size_t)NE * 6);
  float* ln    = alloc((size_t)NN * 128);
  unsigned short* lnb  = (unsigned short*)alloc((size_t)NN * 64);
  float* le    = alloc((size_t)NE * 32);
  unsigned short* leb  = (unsigned short*)alloc((size_t)NE * 16);
  unsigned short* e32b = (unsigned short*)alloc((size_t)NE * 16);   // h2 of ee / ge2 (E,32) bf16
  unsigned short* h1eb = (unsigned short*)alloc((size_t)CH * 64);   // ge1 out (CH,128) bf16
  unsigned short* h1nb = (unsigned short*)alloc((size_t)NN * 128);  // node h1 (N,<=256) bf16
  unsigned short* h2nb = (unsigned short*)alloc((size_t)NN * 64);   // node h2 (N,128) bf16
  unsigned short* aggb = (unsigned short*)alloc((size_t)NN * 16);   // (N,32) bf16
  float* pos   = alloc((size_t)NN * 2);
  float* vel   = alloc((size_t)NN * 2);
  unsigned short* enW1t = (unsigned short*)alloc(40 * 128 / 2);
  unsigned short* enW2t = (unsigned short*)alloc(128 * 128 / 2);
  unsigned short* geW1t = (unsigned short*)alloc(288 * 128 / 2);
  unsigned short* geW2t = (unsigned short*)alloc(128 * 32 / 2);
  unsigned short* gnW1t = (unsigned short*)alloc(160 * 256 / 2);
  unsigned short* gnW2t = (unsigned short*)alloc(256 * 128 / 2);
  unsigned short* dW1t  = (unsigned short*)alloc(128 * 128 / 2);
  float* stat  = alloc(512);
  float* scl   = alloc(256);
  float* shf   = alloc(256);
  float* lacc  = alloc(16);
  int* deg    = (int*)alloc(NN);
  int* coff   = (int*)alloc(NN);
  int* cursor = (int*)alloc(NN);
  int* eidx   = (int*)alloc(2 * (size_t)NE);

  auto WT = [&](const float* W, unsigned short* Wt, int K, int C) {
    wtrans_k<<<(K * C + 255) / 256, 256, 0, stream>>>(W, Wt, K, C);
  };
  WT(en_W1, enW1t, 40, 128);  WT(en_W2, enW2t, 128, 128);
  WT(ge_W1, geW1t, 288, 128); WT(ge_W2, geW2t, 128, 32);
  WT(gn_W1, gnW1t, 160, 256); WT(gn_W2, gnW2t, 256, 128);
  WT(d_W1,  dW1t,  128, 128);

  init_nodes_k<<<(NN + 255) / 256, 256, 0, stream>>>((const float4*)nodes, hist, histb, pos, vel, outGt, NN);
  init_edges_k<<<(NE + 255) / 256, 256, 0, stream>>>((const float4*)nodes, eattr, ep, ef, NE);

  // CSR build (once per call)
  hipMemsetAsync(deg, 0, NN * sizeof(int), stream);
  csr_count_k<<<(NE + 255) / 256, 256, 0, stream>>>(ep, deg, NE);
  csr_scan_k<<<1, 1024, 0, stream>>>(deg, coff, cursor, NN);
  csr_fill_k<<<(NE + 255) / 256, 256, 0, stream>>>(ep, cursor, eidx, NE);

  const int GN = (NN + 63) / 64;          // 313 blocks for BM=64 node gemms
  const int GC = CH / 128;                // 1250 blocks per ge chunk
  const int G_N8  = (NN * 16 + 255) / 256;  // normb C=128 over N
  const int G_E8  = (NE * 4 + 255) / 256;   // normb C=32 over E / le_upd

  for (int r = 0; r < 2; ++r) {
    // ---- node encoder ----
    hipMemsetAsync(stat, 0, 2 * 128 * sizeof(float), stream);
    mgemm_k<40, 128, 64, 2, 2, 1, false, 0><<<GN, 256, 0, stream>>>(histb, nullptr, nullptr, enW1t, en_b1, h1nb, NN, nullptr);
    mgemm_k<128, 128, 64, 2, 2, 1, true, 0><<<GN, 256, 0, stream>>>(h1nb, nullptr, nullptr, enW2t, en_b2, h2nb, NN, stat);
    stats_fin_k<<<1, 256, 0, stream>>>(stat, 1.f / NN, en_g, en_be, scl, shf, 128);
    normb_k<128, false><<<G_N8, 256, 0, stream>>>(h2nb, scl, shf, ln, lnb, NN * 16);

    // ---- edge encoder (fused 2-layer) ----
    hipMemsetAsync(stat, 0, 2 * 32 * sizeof(float), stream);
    ee_fused_k<<<(NE + 255) / 256, 256, 0, stream>>>(ef, ee_W1, ee_b1, ee_W2, ee_b2, e32b, stat, NE);
    stats_fin_k<<<1, 256, 0, stream>>>(stat, 1.f / NE, ee_g, ee_be, scl, shf, 32);
    normb_k<32, false><<<G_E8, 256, 0, stream>>>(e32b, scl, shf, le, leb, NE * 4);

    for (int mp = 0; mp < 2; ++mp) {
      // ---- ge MLP ----
      hipMemsetAsync(stat, 0, 2 * 32 * sizeof(float), stream);
      for (int c = 0; c < 2; ++c) {
        const size_t co = (size_t)c * CH;
        mgemm_k<288, 128, 128, 2, 2, 1, false, 1><<<GC, 256, 0, stream>>>(
            lnb, leb + co * 32, ep + co * 2, geW1t, ge_b1, h1eb, CH, nullptr);
        mgemm_k<128, 32, 128, 4, 1, 1, true, 0><<<GC, 256, 0, stream>>>(
            h1eb, nullptr, nullptr, geW2t, ge_b2, e32b + co * 32, CH, stat);
      }
      stats_fin_k<<<1, 256, 0, stream>>>(stat, 1.f / NE, ge_g, ge_be, scl, shf, 32);

      // ---- aggregation (CSR gather) + le update ----
      gather_agg_k<<<(NN * 64 + 255) / 256, 256, 0, stream>>>(e32b, scl, shf, coff, deg, eidx, aggb, NN);
      le_upd_k<<<G_E8, 256, 0, stream>>>(e32b, scl, shf, le, leb, NE * 4);

      // ---- gn MLP + residual ----
      hipMemsetAsync(stat, 0, 2 * 128 * sizeof(float), stream);
      mgemm_k<160, 256, 64, 2, 2, 1, false, 2><<<GN, 256, 0, stream>>>(lnb, aggb, nullptr, gnW1t, gn_b1, h1nb, NN, nullptr);
      mgemm_k<256, 128, 64, 2, 2, 1, true, 0><<<GN, 256, 0, stream>>>(h1nb, nullptr, nullptr, gnW2t, gn_b2, h2nb, NN, stat);
      stats_fin_k<<<1, 256, 0, stream>>>(stat, 1.f / NN, gn_g, gn_be, scl, shf, 128);
      normb_k<128, true><<<G_N8, 256, 0, stream>>>(h2nb, scl, shf, ln, lnb, NN * 16);
    }

    // ---- decoder + integrate ----
    mgemm_k<128, 128, 64, 2, 2, 2, false, 0><<<GN, 256, 0, stream>>>(lnb, nullptr, nullptr, dW1t, d_b1, h1nb, NN, nullptr);
    dec2i_k<<<(NN + 255) / 256, 256, 0, stream>>>(h1nb, d_W2, d_b2, pos, vel, outPreds + (size_t)r * NN * 2, NN);

    if (r == 0) {
      pd_upd_k<<<(NE + 255) / 256, 256, 0, stream>>>(pos, ep, ef, NE);
      hist_shift_k<<<(NN + 255) / 256, 256, 0, stream>>>(hist, histb, pos, vel, NN);
    }
  }

  hipMemsetAsync(lacc, 0, sizeof(float), stream);
  loss_k<<<(2 * NN * 2 + 255) / 256, 256, 0, stream>>>(outPreds, outGt, lacc);
  loss_write_k<<<1, 1, 0, stream>>>(lacc, outLoss);
}

// Round 3
// 1643.779 us; speedup vs baseline: 2.9852x; 1.1804x over previous
//
#include <hip/hip_runtime.h>

// MeshGraphNet rollout, round 3: all MLPs on bf16 MFMA (incl. edge encoder),
// folded BN-finalize, batched weight transpose + stat memsets.
// N=20000 nodes, E=320000 edges, ROLL=2, MP=2.

constexpr int NN = 20000;
constexpr int NE = 320000;
constexpr int CH = 160000;   // ge chunk (E/2) bounds the E x 128 bf16 intermediate

typedef __attribute__((ext_vector_type(8))) short short8;
typedef __attribute__((ext_vector_type(4))) float f32x4;

__device__ __forceinline__ float act_elu(float x) { return x > 0.f ? x : expm1f(x); }
__device__ __forceinline__ unsigned short f2bf(float f) {
  unsigned u = __builtin_bit_cast(unsigned, f);
  return (unsigned short)((u + 0x7FFFu + ((u >> 16) & 1u)) >> 16);
}
__device__ __forceinline__ float bf2f(unsigned short h) {
  unsigned u = ((unsigned)h) << 16; return __builtin_bit_cast(float, u);
}

// ---------------------------------------------------------------------------
// bf16 MFMA GEMM: out(M,C) = ACT(X(M,K) @ W(K,C) + b), bf16 in/out, f32 acc.
// Wt = W^T bf16 (C,K). 256 threads = 4 waves (NWM x NWC), tile BM x C.
// MODE 0: A is (M,K) bf16.
// MODE 1: edge gather: x(e,k) = k<128 ? A[ep[2e]*128+k] : k<256 ? A[ep[2e+1]*128+k-128] : A2[e*32+k-256]
// MODE 2: node concat: x(n,k) = k<128 ? A[n*128+k] : A2[n*32+k-128]
// MODE 3: A is (M,8) bf16, upper K zero-padded (K must be 32).
// STATS: per-channel sum/sumsq of activated outputs -> stat[0..C),stat[C..2C).
template<int K, int C, int BM, int NWM, int NWC, int ACT, bool STATS, int MODE>
__global__ __launch_bounds__(256) void mgemm_k(
    const unsigned short* __restrict__ A, const unsigned short* __restrict__ A2,
    const int* __restrict__ ep,
    const unsigned short* __restrict__ Wt, const float* __restrict__ bias,
    unsigned short* __restrict__ out, int M, float* __restrict__ stat)
{
  constexpr int FM = BM / (16 * NWM);
  constexpr int FC = C / (16 * NWC);
  constexpr int NKS = (K + 31) / 32;
  constexpr int RB = 40;                       // 32 bf16 + 8 pad per K-step row
  static_assert(NWM * NWC == 4, "4 waves");

  __shared__ unsigned short As[BM * RB];
  __shared__ unsigned short Bs[C * RB];
  __shared__ float red[2][C];
  __shared__ int eps[(MODE == 1) ? BM * 2 : 2];

  const int tid = threadIdx.x;
  const int row0 = blockIdx.x * BM;
  const int wave = tid >> 6, lane = tid & 63;
  const int wm = wave % NWM, wc = wave / NWM;
  const int lr = lane & 15, kg = lane >> 4;

  if (MODE == 1) {
    for (int i = tid; i < BM * 2; i += 256) eps[i] = ep[row0 * 2 + i];
    __syncthreads();
  }

  f32x4 acc[FM][FC];
#pragma unroll
  for (int i = 0; i < FM; ++i)
#pragma unroll
    for (int j = 0; j < FC; ++j) acc[i][j] = (f32x4){0.f, 0.f, 0.f, 0.f};

  for (int ks = 0; ks < NKS; ++ks) {
    const int k0 = ks * 32;
    for (int idx = tid; idx < (BM + C) * 4; idx += 256) {
      uint4 v = make_uint4(0, 0, 0, 0);
      if (idx < BM * 4) {
        int m = idx >> 2, chk = idx & 3;
        int kglob = k0 + chk * 8;
        const unsigned short* src = nullptr;
        if (MODE == 0) {
          int row = row0 + m;
          if (row < M && kglob + 8 <= K) src = A + (size_t)row * K + kglob;
        } else if (MODE == 1) {
          int e = row0 + m;
          if (kglob < 128)      src = A + (size_t)eps[2 * m] * 128 + kglob;
          else if (kglob < 256) src = A + (size_t)eps[2 * m + 1] * 128 + (kglob - 128);
          else                  src = A2 + (size_t)e * 32 + (kglob - 256);
        } else if (MODE == 2) {
          int row = row0 + m;
          if (row < M) {
            if (kglob < 128) src = A + (size_t)row * 128 + kglob;
            else             src = A2 + (size_t)row * 32 + (kglob - 128);
          }
        } else {  // MODE 3
          int row = row0 + m;
          if (row < M && chk == 0) src = A + (size_t)row * 8;
        }
        if (src) v = *(const uint4*)src;
        *(uint4*)&As[m * RB + chk * 8] = v;
      } else {
        int i2 = idx - BM * 4;
        int c = i2 >> 2, chk = i2 & 3;
        int kglob = k0 + chk * 8;
        if (kglob + 8 <= K) v = *(const uint4*)&Wt[(size_t)c * K + kglob];
        *(uint4*)&Bs[c * RB + chk * 8] = v;
      }
    }
    __syncthreads();

    short8 af[FM], bfr[FC];
#pragma unroll
    for (int i = 0; i < FM; ++i) {
      int r = (wm * FM + i) * 16 + lr;
      af[i] = __builtin_bit_cast(short8, *(const uint4*)&As[r * RB + kg * 8]);
    }
#pragma unroll
    for (int j = 0; j < FC; ++j) {
      int c = (wc * FC + j) * 16 + lr;
      bfr[j] = __builtin_bit_cast(short8, *(const uint4*)&Bs[c * RB + kg * 8]);
    }
#pragma unroll
    for (int i = 0; i < FM; ++i)
#pragma unroll
      for (int j = 0; j < FC; ++j)
        acc[i][j] = __builtin_amdgcn_mfma_f32_16x16x32_bf16(af[i], bfr[j], acc[i][j], 0, 0, 0);
    __syncthreads();
  }

  float psum[FC], psq[FC], bl[FC];
#pragma unroll
  for (int j = 0; j < FC; ++j) {
    psum[j] = 0.f; psq[j] = 0.f;
    bl[j] = bias[(wc * FC + j) * 16 + lr];
  }
#pragma unroll
  for (int i = 0; i < FM; ++i) {
#pragma unroll
    for (int t = 0; t < 4; ++t) {
      int row = row0 + (wm * FM + i) * 16 + kg * 4 + t;
      bool ok = row < M;
#pragma unroll
      for (int j = 0; j < FC; ++j) {
        float v = acc[i][j][t] + bl[j];
        if (ACT == 1) v = act_elu(v);
        else if (ACT == 2) v = tanhf(v);
        if (ok) {
          out[(size_t)row * C + (wc * FC + j) * 16 + lr] = f2bf(v);
          if (STATS) { psum[j] += v; psq[j] += v * v; }
        }
      }
    }
  }

  if (STATS) {
    for (int i = tid; i < 2 * C; i += 256) ((float*)red)[i] = 0.f;
    __syncthreads();
#pragma unroll
    for (int j = 0; j < FC; ++j) {
      int c = (wc * FC + j) * 16 + lr;
      atomicAdd(&red[0][c], psum[j]);
      atomicAdd(&red[1][c], psq[j]);
    }
    __syncthreads();
    for (int i = tid; i < C; i += 256) {
      atomicAdd(&stat[i], red[0][i]);
      atomicAdd(&stat[C + i], red[1][i]);
    }
  }
}

// All weight transposes (f32 (K,C) -> bf16 (C,K), zero-pad beyond KS) in one kernel.
__global__ __launch_bounds__(256) void wtrans_all_k(
    const float* __restrict__ enW1, const float* __restrict__ enW2,
    const float* __restrict__ geW1, const float* __restrict__ geW2,
    const float* __restrict__ gnW1, const float* __restrict__ gnW2,
    const float* __restrict__ dW1,  const float* __restrict__ eeW1,
    const float* __restrict__ eeW2,
    unsigned short* __restrict__ enW1t, unsigned short* __restrict__ enW2t,
    unsigned short* __restrict__ geW1t, unsigned short* __restrict__ geW2t,
    unsigned short* __restrict__ gnW1t, unsigned short* __restrict__ gnW2t,
    unsigned short* __restrict__ dW1t,  unsigned short* __restrict__ eeW1t,
    unsigned short* __restrict__ eeW2t)
{
  int i = blockIdx.x * 256 + threadIdx.x;
#define SEG(Wsrc, Wdst, KK, CC, KS) \
  { int n = (KK) * (CC); \
    if (i < n) { int c = i / (KK), k = i - c * (KK); \
      Wdst[i] = (k < (KS)) ? f2bf(Wsrc[(size_t)k * (CC) + c]) : (unsigned short)0; return; } \
    i -= n; }
  SEG(enW1, enW1t, 40, 128, 40)
  SEG(enW2, enW2t, 128, 128, 128)
  SEG(geW1, geW1t, 288, 128, 288)
  SEG(geW2, geW2t, 128, 32, 128)
  SEG(gnW1, gnW1t, 160, 256, 160)
  SEG(gnW2, gnW2t, 256, 128, 256)
  SEG(dW1,  dW1t,  128, 128, 128)
  SEG(eeW1, eeW1t, 32, 32, 6)
  SEG(eeW2, eeW2t, 32, 32, 32)
#undef SEG
}
constexpr int WT_TOTAL = 40*128 + 128*128 + 288*128 + 128*32 + 160*256 + 256*128 + 128*128 + 32*32 + 32*32;

// out(f32) = h(bf16)*scl + shf (+ out if RES); writes bf16 mirror. BN finalize folded.
template<int C, bool RES>
__global__ __launch_bounds__(256) void normb_k(const unsigned short* __restrict__ h,
    const float* __restrict__ stat, float invM,
    const float* __restrict__ g, const float* __restrict__ be,
    float* __restrict__ out, unsigned short* __restrict__ out_bf, int total8)
{
  __shared__ float s_scl[C], s_shf[C];
  for (int i = threadIdx.x; i < C; i += 256) {
    float mu = stat[i] * invM;
    float var = stat[C + i] * invM - mu * mu;
    float s = rsqrtf(var + 1e-5f) * g[i];
    s_scl[i] = s; s_shf[i] = be[i] - mu * s;
  }
  __syncthreads();
  int i = blockIdx.x * 256 + threadIdx.x;
  if (i >= total8) return;
  int c8 = (i % (C / 8)) * 8;
  uint4 hv = ((const uint4*)h)[i];
  const unsigned short* hp = (const unsigned short*)&hv;
  float f[8];
#pragma unroll
  for (int j = 0; j < 8; ++j) f[j] = fmaf(bf2f(hp[j]), s_scl[c8 + j], s_shf[c8 + j]);
  if (RES) {
    float4 p0 = ((const float4*)out)[2 * i], p1 = ((const float4*)out)[2 * i + 1];
    f[0] += p0.x; f[1] += p0.y; f[2] += p0.z; f[3] += p0.w;
    f[4] += p1.x; f[5] += p1.y; f[6] += p1.z; f[7] += p1.w;
  }
  ((float4*)out)[2 * i]     = make_float4(f[0], f[1], f[2], f[3]);
  ((float4*)out)[2 * i + 1] = make_float4(f[4], f[5], f[6], f[7]);
  uint4 o;
  unsigned short* op = (unsigned short*)&o;
#pragma unroll
  for (int j = 0; j < 8; ++j) op[j] = f2bf(f[j]);
  ((uint4*)out_bf)[i] = o;
}

// ---- CSR build ----
__global__ __launch_bounds__(256) void csr_count_k(const int* __restrict__ ep,
    int* __restrict__ deg, int E)
{
  int e = blockIdx.x * 256 + threadIdx.x;
  if (e < E) { atomicAdd(&deg[ep[2 * e]], 1); atomicAdd(&deg[ep[2 * e + 1]], 1); }
}

__global__ __launch_bounds__(1024) void csr_scan_k(const int* __restrict__ deg,
    int* __restrict__ off, int* __restrict__ cursor, int N)
{
  __shared__ int part[1024];
  int t = threadIdx.x;
  const int CHK = (N + 1023) / 1024;
  int c0 = t * CHK, c1 = min(c0 + CHK, N);
  int s = 0;
  for (int i = c0; i < c1; ++i) s += deg[i];
  part[t] = s;
  __syncthreads();
  for (int o = 1; o < 1024; o <<= 1) {
    int v = (t >= o) ? part[t - o] : 0;
    __syncthreads();
    part[t] += v;
    __syncthreads();
  }
  int run = t ? part[t - 1] : 0;
  for (int i = c0; i < c1; ++i) { int d = deg[i]; off[i] = run; cursor[i] = run; run += d; }
}

__global__ __launch_bounds__(256) void csr_fill_k(const int* __restrict__ ep,
    int* __restrict__ cursor, int* __restrict__ eidx, int E)
{
  int e = blockIdx.x * 256 + threadIdx.x;
  if (e < E) {
    int p0 = atomicAdd(&cursor[ep[2 * e]], 1); eidx[p0] = e;
    int p1 = atomicAdd(&cursor[ep[2 * e + 1]], 1); eidx[p1] = e;
  }
}

// agg_bf[n][c] = scl[c]*sum_e h2e[e][c] + deg[n]*shf[c]  (one wave/node, finalize folded)
__global__ __launch_bounds__(256) void gather_agg_k(const unsigned short* __restrict__ h2e,
    const float* __restrict__ stat, float invM,
    const float* __restrict__ g, const float* __restrict__ be,
    const int* __restrict__ off, const int* __restrict__ deg, const int* __restrict__ eidx,
    unsigned short* __restrict__ agg_bf, int N)
{
  __shared__ float s_scl[32], s_shf[32];
  if (threadIdx.x < 32) {
    int c = threadIdx.x;
    float mu = stat[c] * invM;
    float var = stat[32 + c] * invM - mu * mu;
    float s = rsqrtf(var + 1e-5f) * g[c];
    s_scl[c] = s; s_shf[c] = be[c] - mu * s;
  }
  __syncthreads();
  int wid = (blockIdx.x * 256 + threadIdx.x) >> 6;
  if (wid >= N) return;
  int lane = threadIdx.x & 63;
  int c = lane & 31, half = lane >> 5;
  int o = off[wid], d = deg[wid];
  float s = 0.f;
  for (int i = half; i < d; i += 2) {
    int e = eidx[o + i];
    s += bf2f(h2e[(size_t)e * 32 + c]);
  }
  s += __shfl_down(s, 32, 64);
  if (half == 0) {
    float v = fmaf(s_scl[c], s, (float)d * s_shf[c]);
    agg_bf[(size_t)wid * 32 + c] = f2bf(v);
  }
}

// le(f32) += h2e*scl+shf ; refresh le bf16 mirror (finalize folded)
__global__ __launch_bounds__(256) void le_upd_k(const unsigned short* __restrict__ h2e,
    const float* __restrict__ stat, float invM,
    const float* __restrict__ g, const float* __restrict__ be,
    float* __restrict__ le, unsigned short* __restrict__ le_bf, int total8)
{
  __shared__ float s_scl[32], s_shf[32];
  if (threadIdx.x < 32) {
    int c = threadIdx.x;
    float mu = stat[c] * invM;
    float var = stat[32 + c] * invM - mu * mu;
    float s = rsqrtf(var + 1e-5f) * g[c];
    s_scl[c] = s; s_shf[c] = be[c] - mu * s;
  }
  __syncthreads();
  int i = blockIdx.x * 256 + threadIdx.x;
  if (i >= total8) return;
  int c8 = (i & 3) * 8;
  uint4 hv = ((const uint4*)h2e)[i];
  const unsigned short* hp = (const unsigned short*)&hv;
  float4 l0 = ((const float4*)le)[2 * i], l1 = ((const float4*)le)[2 * i + 1];
  float f[8] = {l0.x, l0.y, l0.z, l0.w, l1.x, l1.y, l1.z, l1.w};
#pragma unroll
  for (int j = 0; j < 8; ++j) f[j] += fmaf(bf2f(hp[j]), s_scl[c8 + j], s_shf[c8 + j]);
  ((float4*)le)[2 * i]     = make_float4(f[0], f[1], f[2], f[3]);
  ((float4*)le)[2 * i + 1] = make_float4(f[4], f[5], f[6], f[7]);
  uint4 o;
  unsigned short* op = (unsigned short*)&o;
#pragma unroll
  for (int j = 0; j < 8; ++j) op[j] = f2bf(f[j]);
  ((uint4*)le_bf)[i] = o;
}

// decoder layer2 (128->2, bf16 in) + integrate + preds
__global__ __launch_bounds__(256) void dec2i_k(const unsigned short* __restrict__ T,
    const float* __restrict__ W2, const float* __restrict__ b2,
    float* __restrict__ pos, float* __restrict__ vel, float* __restrict__ preds, int M)
{
  __shared__ float Wl[256];
  Wl[threadIdx.x] = W2[threadIdx.x];
  __syncthreads();
  int row = blockIdx.x * 256 + threadIdx.x;
  if (row >= M) return;
  float ax = b2[0], ay = b2[1];
  const uint4* t4 = (const uint4*)(T + (size_t)row * 128);
#pragma unroll
  for (int k8 = 0; k8 < 16; ++k8) {
    uint4 v = t4[k8];
    const unsigned short* p = (const unsigned short*)&v;
#pragma unroll
    for (int j = 0; j < 8; ++j) {
      float f = bf2f(p[j]);
      int k = k8 * 8 + j;
      ax = fmaf(f, Wl[2 * k], ax);
      ay = fmaf(f, Wl[2 * k + 1], ay);
    }
  }
  float2 p = ((float2*)pos)[row], vv = ((float2*)vel)[row];
  p.x += ax; p.y += ay; vv.x += ax; vv.y += ay;
  ((float2*)pos)[row] = p; ((float2*)vel)[row] = vv;
  ((float2*)preds)[row] = p;
}

// edge_feat channels 4,5 = |pos[s0]-pos[s1]| (bf16, packed u32 store)
__global__ __launch_bounds__(256) void pd_upd_k(const float* __restrict__ pos,
    const int* __restrict__ ep, unsigned short* __restrict__ efb, int E)
{
  int e = blockIdx.x * 256 + threadIdx.x;
  if (e >= E) return;
  float2 p0 = ((const float2*)pos)[ep[2 * e]];
  float2 p1 = ((const float2*)pos)[ep[2 * e + 1]];
  unsigned u = (unsigned)f2bf(fabsf(p0.x - p1.x)) | ((unsigned)f2bf(fabsf(p0.y - p1.y)) << 16);
  *(unsigned*)&efb[(size_t)e * 8 + 4] = u;
}

__global__ __launch_bounds__(256) void hist_shift_k(float* __restrict__ hist,
    unsigned short* __restrict__ histb,
    const float* __restrict__ pos, const float* __restrict__ vel, int M)
{
  int n = blockIdx.x * 256 + threadIdx.x;
  if (n >= M) return;
  float4* h4 = (float4*)(hist + (size_t)n * 40);
  float4 tmp[10];
#pragma unroll
  for (int t = 0; t < 10; ++t) tmp[t] = h4[t];
  float2 pp = ((const float2*)pos)[n], vv = ((const float2*)vel)[n];
  unsigned* hb = (unsigned*)(histb + (size_t)n * 40);
#pragma unroll
  for (int t = 0; t < 9; ++t) {
    float4 v = tmp[t + 1];
    h4[t] = v;
    hb[2 * t]     = (unsigned)f2bf(v.x) | ((unsigned)f2bf(v.y) << 16);
    hb[2 * t + 1] = (unsigned)f2bf(v.z) | ((unsigned)f2bf(v.w) << 16);
  }
  float4 nv = make_float4(pp.x, pp.y, vv.x, vv.y);
  h4[9] = nv;
  hb[18] = (unsigned)f2bf(nv.x) | ((unsigned)f2bf(nv.y) << 16);
  hb[19] = (unsigned)f2bf(nv.z) | ((unsigned)f2bf(nv.w) << 16);
}

__global__ __launch_bounds__(256) void init_nodes_k(const float4* __restrict__ nodes4,
    float* __restrict__ hist, unsigned short* __restrict__ histb,
    float* __restrict__ pos, float* __restrict__ vel,
    float* __restrict__ outGt, int M)
{
  int n = blockIdx.x * 256 + threadIdx.x;
  if (n >= M) return;
  float4* h4 = (float4*)(hist + (size_t)n * 40);
  unsigned* hb = (unsigned*)(histb + (size_t)n * 40);
  float4 v;
#pragma unroll
  for (int t = 0; t < 10; ++t) {
    v = nodes4[(size_t)t * M + n];
    h4[t] = v;
    hb[2 * t]     = (unsigned)f2bf(v.x) | ((unsigned)f2bf(v.y) << 16);
    hb[2 * t + 1] = (unsigned)f2bf(v.z) | ((unsigned)f2bf(v.w) << 16);
  }
  ((float2*)pos)[n] = make_float2(v.x, v.y);
  ((float2*)vel)[n] = make_float2(v.z, v.w);
  float4 g0 = nodes4[(size_t)10 * M + n];
  float4 g1 = nodes4[(size_t)11 * M + n];
  float2* gt2 = (float2*)outGt;
  gt2[(size_t)2 * n + 0] = make_float2(g0.x, g0.y);
  gt2[(size_t)2 * n + 1] = make_float2(g0.z, g0.w);
  gt2[(size_t)2 * (M + n) + 0] = make_float2(g1.x, g1.y);
  gt2[(size_t)2 * (M + n) + 1] = make_float2(g1.z, g1.w);
}

// edge_feat init as bf16 (E,8): [attr0, attr1, pd0 x4, 0, 0]
__global__ __launch_bounds__(256) void init_edges_k(const float4* __restrict__ nodes4,
    const float* __restrict__ attr, const int* __restrict__ ep,
    unsigned short* __restrict__ efb, int E)
{
  int e = blockIdx.x * 256 + threadIdx.x;
  if (e >= E) return;
  float4 w0 = nodes4[(size_t)10 * NN + ep[2 * e]];
  float4 w1 = nodes4[(size_t)10 * NN + ep[2 * e + 1]];
  float2 a = ((const float2*)attr)[e];
  uint4 o;
  o.x = (unsigned)f2bf(a.x) | ((unsigned)f2bf(a.y) << 16);
  o.y = (unsigned)f2bf(fabsf(w0.x - w1.x)) | ((unsigned)f2bf(fabsf(w0.y - w1.y)) << 16);
  o.z = (unsigned)f2bf(fabsf(w0.z - w1.z)) | ((unsigned)f2bf(fabsf(w0.w - w1.w)) << 16);
  o.w = 0;
  ((uint4*)efb)[e] = o;
}

__global__ __launch_bounds__(256) void loss_k(const float* __restrict__ preds,
    const float* __restrict__ gtf, float* __restrict__ acc)
{
  int i = blockIdx.x * 256 + threadIdx.x;
  float d2 = 0.f;
  if (i < 2 * NN * 2) {
    int r = i / (NN * 2);
    int rem = i - r * (NN * 2);
    int n = rem >> 1, c = rem & 1;
    float df = preds[i] - gtf[((size_t)r * NN + n) * 4 + c];
    d2 = df * df;
  }
#pragma unroll
  for (int o = 32; o > 0; o >>= 1) d2 += __shfl_down(d2, o, 64);
  __shared__ float sb[4];
  int lane = threadIdx.x & 63, w = threadIdx.x >> 6;
  if (lane == 0) sb[w] = d2;
  __syncthreads();
  if (threadIdx.x == 0) atomicAdd(acc, sb[0] + sb[1] + sb[2] + sb[3]);
}

__global__ void loss_write_k(const float* __restrict__ acc, float* __restrict__ o)
{
  float s = *acc;
  o[0] = s * 0.25f;
  o[1] = s * (1.f / 80000.f);
}

extern "C" void kernel_launch(void* const* d_in, const int* in_sizes, int n_in,
                              void* d_out, int out_size, void* d_ws, size_t ws_size,
                              hipStream_t stream)
{
  (void)in_sizes; (void)n_in; (void)out_size; (void)ws_size;
  const float* nodes = (const float*)d_in[0];
  const int*   ep    = (const int*)d_in[1];
  const float* eattr = (const float*)d_in[2];
  const float *en_W1 = (const float*)d_in[3],  *en_b1 = (const float*)d_in[4],
              *en_W2 = (const float*)d_in[5],  *en_b2 = (const float*)d_in[6],
              *en_g  = (const float*)d_in[7],  *en_be = (const float*)d_in[8];
  const float *ee_W1 = (const float*)d_in[9],  *ee_b1 = (const float*)d_in[10],
              *ee_W2 = (const float*)d_in[11], *ee_b2 = (const float*)d_in[12],
              *ee_g  = (const float*)d_in[13], *ee_be = (const float*)d_in[14];
  const float *ge_W1 = (const float*)d_in[15], *ge_b1 = (const float*)d_in[16],
              *ge_W2 = (const float*)d_in[17], *ge_b2 = (const float*)d_in[18],
              *ge_g  = (const float*)d_in[19], *ge_be = (const float*)d_in[20];
  const float *gn_W1 = (const float*)d_in[21], *gn_b1 = (const float*)d_in[22],
              *gn_W2 = (const float*)d_in[23], *gn_b2 = (const float*)d_in[24],
              *gn_g  = (const float*)d_in[25], *gn_be = (const float*)d_in[26];
  const float *d_W1  = (const float*)d_in[27], *d_b1  = (const float*)d_in[28],
              *d_W2  = (const float*)d_in[29], *d_b2  = (const float*)d_in[30];

  float* out = (float*)d_out;
  float* outPreds = out;
  float* outLoss  = out + 80000;
  float* outGt    = out + 80002;

  float* ws = (float*)d_ws;
  size_t off = 0;
  auto alloc = [&](size_t nf) { float* p = ws + off; off += (nf + 15) & ~(size_t)15; return p; };
  float* hist  = alloc((size_t)NN * 40);
  unsigned short* histb = (unsigned short*)alloc((size_t)NN * 20);
  unsigned short* efb   = (unsigned short*)alloc((size_t)NE * 4);    // (E,8) bf16
  float* ln    = alloc((size_t)NN * 128);
  unsigned short* lnb  = (unsigned short*)alloc((size_t)NN * 64);
  float* le    = alloc((size_t)NE * 32);
  unsigned short* leb  = (unsigned short*)alloc((size_t)NE * 16);
  unsigned short* e32b = (unsigned short*)alloc((size_t)NE * 16);    // ee-h2 / ge2 out (E,32) bf16
  unsigned short* h1eb = (unsigned short*)alloc((size_t)CH * 64);    // ge1 out (CH,128); aliases ee-h1 (E,32)
  unsigned short* h1nb = (unsigned short*)alloc((size_t)NN * 128);   // node h1 (N,<=256) bf16
  unsigned short* h2nb = (unsigned short*)alloc((size_t)NN * 64);    // node h2 (N,128) bf16
  unsigned short* aggb = (unsigned short*)alloc((size_t)NN * 16);    // (N,32) bf16
  float* pos   = alloc((size_t)NN * 2);
  float* vel   = alloc((size_t)NN * 2);
  unsigned short* enW1t = (unsigned short*)alloc(40 * 128 / 2);
  unsigned short* enW2t = (unsigned short*)alloc(128 * 128 / 2);
  unsigned short* geW1t = (unsigned short*)alloc(288 * 128 / 2);
  unsigned short* geW2t = (unsigned short*)alloc(128 * 32 / 2);
  unsigned short* gnW1t = (unsigned short*)alloc(160 * 256 / 2);
  unsigned short* gnW2t = (unsigned short*)alloc(256 * 128 / 2);
  unsigned short* dW1t  = (unsigned short*)alloc(128 * 128 / 2);
  unsigned short* eeW1t = (unsigned short*)alloc(32 * 32 / 2);
  unsigned short* eeW2t = (unsigned short*)alloc(32 * 32 / 2);
  float* statArr = alloc(12 * 256 + 16);     // 12 BN-stat slots + loss acc
  float* lacc    = statArr + 12 * 256;
  int* deg    = (int*)alloc(NN);
  int* coff   = (int*)alloc(NN);
  int* cursor = (int*)alloc(NN);
  int* eidx   = (int*)alloc(2 * (size_t)NE);

  // one memset for all stat slots + loss accumulator; one for CSR degree
  hipMemsetAsync(statArr, 0, (12 * 256 + 16) * sizeof(float), stream);
  hipMemsetAsync(deg, 0, NN * sizeof(int), stream);

  wtrans_all_k<<<(WT_TOTAL + 255) / 256, 256, 0, stream>>>(
      en_W1, en_W2, ge_W1, ge_W2, gn_W1, gn_W2, d_W1, ee_W1, ee_W2,
      enW1t, enW2t, geW1t, geW2t, gnW1t, gnW2t, dW1t, eeW1t, eeW2t);

  init_nodes_k<<<(NN + 255) / 256, 256, 0, stream>>>((const float4*)nodes, hist, histb, pos, vel, outGt, NN);
  init_edges_k<<<(NE + 255) / 256, 256, 0, stream>>>((const float4*)nodes, eattr, ep, efb, NE);

  csr_count_k<<<(NE + 255) / 256, 256, 0, stream>>>(ep, deg, NE);
  csr_scan_k<<<1, 1024, 0, stream>>>(deg, coff, cursor, NN);
  csr_fill_k<<<(NE + 255) / 256, 256, 0, stream>>>(ep, cursor, eidx, NE);

  const int GN = (NN + 63) / 64;            // node gemms, BM=64
  const int GE = NE / 128;                  // 2500: edge gemms, BM=128
  const int GC = CH / 128;                  // 1250: ge chunk gemms
  const int G_N8 = (NN * 16 + 255) / 256;   // normb C=128 over N
  const int G_E8 = (NE * 4 + 255) / 256;    // normb C=32 over E / le_upd

  for (int r = 0; r < 2; ++r) {
    float* sEN = statArr + (r * 6 + 0) * 256;
    float* sEE = statArr + (r * 6 + 1) * 256;

    // ---- node encoder ----
    mgemm_k<40, 128, 64, 2, 2, 1, false, 0><<<GN, 256, 0, stream>>>(histb, nullptr, nullptr, enW1t, en_b1, h1nb, NN, nullptr);
    mgemm_k<128, 128, 64, 2, 2, 1, true, 0><<<GN, 256, 0, stream>>>(h1nb, nullptr, nullptr, enW2t, en_b2, h2nb, NN, sEN);
    normb_k<128, false><<<G_N8, 256, 0, stream>>>(h2nb, sEN, 1.f / NN, en_g, en_be, ln, lnb, NN * 16);

    // ---- edge encoder (MFMA, K zero-padded to 32) ----
    mgemm_k<32, 32, 128, 4, 1, 1, false, 3><<<GE, 256, 0, stream>>>(efb, nullptr, nullptr, eeW1t, ee_b1, h1eb, NE, nullptr);
    mgemm_k<32, 32, 128, 4, 1, 1, true, 0><<<GE, 256, 0, stream>>>(h1eb, nullptr, nullptr, eeW2t, ee_b2, e32b, NE, sEE);
    normb_k<32, false><<<G_E8, 256, 0, stream>>>(e32b, sEE, 1.f / NE, ee_g, ee_be, le, leb, NE * 4);

    for (int mp = 0; mp < 2; ++mp) {
      float* sGE = statArr + (r * 6 + 2 + mp * 2) * 256;
      float* sGN = statArr + (r * 6 + 3 + mp * 2) * 256;

      // ---- ge MLP (chunked over E) ----
      for (int c = 0; c < 2; ++c) {
        const size_t co = (size_t)c * CH;
        mgemm_k<288, 128, 128, 2, 2, 1, false, 1><<<GC, 256, 0, stream>>>(
            lnb, leb + co * 32, ep + co * 2, geW1t, ge_b1, h1eb, CH, nullptr);
        mgemm_k<128, 32, 128, 4, 1, 1, true, 0><<<GC, 256, 0, stream>>>(
            h1eb, nullptr, nullptr, geW2t, ge_b2, e32b + co * 32, CH, sGE);
      }

      // ---- aggregation (CSR gather) + le update (BN finalize folded) ----
      gather_agg_k<<<(NN * 64 + 255) / 256, 256, 0, stream>>>(e32b, sGE, 1.f / NE, ge_g, ge_be, coff, deg, eidx, aggb, NN);
      le_upd_k<<<G_E8, 256, 0, stream>>>(e32b, sGE, 1.f / NE, ge_g, ge_be, le, leb, NE * 4);

      // ---- gn MLP + residual ----
      mgemm_k<160, 256, 64, 2, 2, 1, false, 2><<<GN, 256, 0, stream>>>(lnb, aggb, nullptr, gnW1t, gn_b1, h1nb, NN, nullptr);
      mgemm_k<256, 128, 64, 2, 2, 1, true, 0><<<GN, 256, 0, stream>>>(h1nb, nullptr, nullptr, gnW2t, gn_b2, h2nb, NN, sGN);
      normb_k<128, true><<<G_N8, 256, 0, stream>>>(h2nb, sGN, 1.f / NN, gn_g, gn_be, ln, lnb, NN * 16);
    }

    // ---- decoder + integrate ----
    mgemm_k<128, 128, 64, 2, 2, 2, false, 0><<<GN, 256, 0, stream>>>(lnb, nullptr, nullptr, dW1t, d_b1, h1nb, NN, nullptr);
    dec2i_k<<<(NN + 255) / 256, 256, 0, stream>>>(h1nb, d_W2, d_b2, pos, vel, outPreds + (size_t)r * NN * 2, NN);

    if (r == 0) {
      pd_upd_k<<<(NE + 255) / 256, 256, 0, stream>>>(pos, ep, efb, NE);
      hist_shift_k<<<(NN + 255) / 256, 256, 0, stream>>>(hist, histb, pos, vel, NN);
    }
  }

  loss_k<<<(2 * NN * 2 + 255) / 256, 256, 0, stream>>>(outPreds, outGt, lacc);
  loss_write_k<<<1, 1, 0, stream>>>(lacc, outLoss);
}

// Round 4
// 1419.935 us; speedup vs baseline: 3.4558x; 1.1576x over previous
//
#include <hip/hip_runtime.h>

// MeshGraphNet rollout, round 4: fused 2-layer MFMA MLPs (h1 stays in LDS),
// LDS-repacked coalesced stores, no E x 128 HBM intermediate.
// N=20000 nodes, E=320000 edges, ROLL=2, MP=2.

constexpr int NN = 20000;
constexpr int NE = 320000;

typedef __attribute__((ext_vector_type(8))) short short8;
typedef __attribute__((ext_vector_type(4))) float f32x4;

__device__ __forceinline__ float act_elu(float x) { return x > 0.f ? x : expm1f(x); }
__device__ __forceinline__ unsigned short f2bf(float f) {
  unsigned u = __builtin_bit_cast(unsigned, f);
  return (unsigned short)((u + 0x7FFFu + ((u >> 16) & 1u)) >> 16);
}
__device__ __forceinline__ float bf2f(unsigned short h) {
  unsigned u = ((unsigned)h) << 16; return __builtin_bit_cast(float, u);
}

// ---------------------------------------------------------------------------
// Fused 2-layer MLP on MFMA:
//   h1 = elu(X @ W1 + b1)  (h1 kept in LDS as bf16)
//   out = ACT2(h1 @ W2 + b2)  (bf16 out via LDS-repacked coalesced stores)
// Wt1 (C1,K1) bf16, Wt2 (C2,C1) bf16 (both pre-transposed).
// MODE 0: X = A (M,K1) bf16 rows.
// MODE 1: edge gather: x(e,k) = k<128 ? A[ep0*128+k] : k<256 ? A[ep1*128+k-128] : A2[e*32+k-256]
// MODE 2: node concat: x(n,k) = k<128 ? A[n*128+k] : A2[n*32+k-128]
// MODE 3: X = A (M,8) bf16, K1 zero-padded to 32.
// STATS: per-channel sum/sumsq of final outputs -> stat[0..C2), stat[C2..2C2).
template<int K1, int C1, int C2, int BM, int NWM, int NWC, int NWM2, int NWC2,
         int ACT2, bool STATS, int MODE>
__global__ __launch_bounds__(256) void mlp2_k(
    const unsigned short* __restrict__ A, const unsigned short* __restrict__ A2,
    const int* __restrict__ ep,
    const unsigned short* __restrict__ Wt1, const float* __restrict__ b1,
    const unsigned short* __restrict__ Wt2, const float* __restrict__ b2,
    unsigned short* __restrict__ out, int M, float* __restrict__ stat)
{
  constexpr int FM  = BM / (16 * NWM);
  constexpr int FC  = C1 / (16 * NWC);
  constexpr int FM2 = BM / (16 * NWM2);
  constexpr int FC2 = C2 / (16 * NWC2);
  constexpr int NKS1 = (K1 + 31) / 32;
  constexpr int NKS2 = C1 / 32;
  constexpr int RB = 40;            // staging row stride (shorts): 32 + 8 pad
  constexpr int P1 = C1 + 8;        // h1 LDS row stride (shorts)
  constexpr int P2 = C2 + 8;        // out-copy LDS row stride (shorts)
  static_assert(NWM * NWC == 4 && NWM2 * NWC2 == 4, "4 waves");

  __shared__ unsigned short As[BM * RB];
  __shared__ unsigned short Bs[C1 * RB];
  __shared__ unsigned short H1[BM * P1];
  __shared__ float red[2][C2];
  __shared__ int eps[(MODE == 1) ? BM * 2 : 2];

  const int tid = threadIdx.x;
  const int row0 = blockIdx.x * BM;
  const int wave = tid >> 6, lane = tid & 63;
  const int wm = wave % NWM, wc = wave / NWM;
  const int wm2 = wave % NWM2, wc2 = wave / NWM2;
  const int lr = lane & 15, kg = lane >> 4;

  if (MODE == 1) {
    for (int i = tid; i < BM * 2; i += 256) eps[i] = ep[row0 * 2 + i];
    __syncthreads();
  }

  // ---------------- stage 1: X @ W1 ----------------
  f32x4 acc1[FM][FC];
#pragma unroll
  for (int i = 0; i < FM; ++i)
#pragma unroll
    for (int j = 0; j < FC; ++j) acc1[i][j] = (f32x4){0.f, 0.f, 0.f, 0.f};

  for (int ks = 0; ks < NKS1; ++ks) {
    const int k0 = ks * 32;
    for (int idx = tid; idx < (BM + C1) * 4; idx += 256) {
      uint4 v = make_uint4(0, 0, 0, 0);
      if (idx < BM * 4) {
        int m = idx >> 2, chk = idx & 3;
        int kglob = k0 + chk * 8;
        const unsigned short* src = nullptr;
        if (MODE == 0) {
          int row = row0 + m;
          if (row < M && kglob + 8 <= K1) src = A + (size_t)row * K1 + kglob;
        } else if (MODE == 1) {
          int e = row0 + m;
          if (kglob < 128)      src = A + (size_t)eps[2 * m] * 128 + kglob;
          else if (kglob < 256) src = A + (size_t)eps[2 * m + 1] * 128 + (kglob - 128);
          else                  src = A2 + (size_t)e * 32 + (kglob - 256);
        } else if (MODE == 2) {
          int row = row0 + m;
          if (row < M) {
            if (kglob < 128) src = A + (size_t)row * 128 + kglob;
            else             src = A2 + (size_t)row * 32 + (kglob - 128);
          }
        } else {  // MODE 3: (M,8) rows, only chk 0 real
          int row = row0 + m;
          if (row < M && chk == 0) src = A + (size_t)row * 8;
        }
        if (src) v = *(const uint4*)src;
        *(uint4*)&As[m * RB + chk * 8] = v;
      } else {
        int i2 = idx - BM * 4;
        int c = i2 >> 2, chk = i2 & 3;
        int kglob = k0 + chk * 8;
        if (kglob + 8 <= K1) v = *(const uint4*)&Wt1[(size_t)c * K1 + kglob];
        *(uint4*)&Bs[c * RB + chk * 8] = v;
      }
    }
    __syncthreads();

    short8 af[FM], bfr[FC];
#pragma unroll
    for (int i = 0; i < FM; ++i) {
      int r = (wm * FM + i) * 16 + lr;
      af[i] = __builtin_bit_cast(short8, *(const uint4*)&As[r * RB + kg * 8]);
    }
#pragma unroll
    for (int j = 0; j < FC; ++j) {
      int c = (wc * FC + j) * 16 + lr;
      bfr[j] = __builtin_bit_cast(short8, *(const uint4*)&Bs[c * RB + kg * 8]);
    }
#pragma unroll
    for (int i = 0; i < FM; ++i)
#pragma unroll
      for (int j = 0; j < FC; ++j)
        acc1[i][j] = __builtin_amdgcn_mfma_f32_16x16x32_bf16(af[i], bfr[j], acc1[i][j], 0, 0, 0);
    __syncthreads();
  }

  // bias + ELU -> H1 (bf16 in LDS). OOB rows hold elu(b1) garbage; guarded later.
  {
    float bl1[FC];
#pragma unroll
    for (int j = 0; j < FC; ++j) bl1[j] = b1[(wc * FC + j) * 16 + lr];
#pragma unroll
    for (int i = 0; i < FM; ++i)
#pragma unroll
      for (int t = 0; t < 4; ++t) {
        int rl = (wm * FM + i) * 16 + kg * 4 + t;
#pragma unroll
        for (int j = 0; j < FC; ++j) {
          float v = act_elu(acc1[i][j][t] + bl1[j]);
          H1[rl * P1 + (wc * FC + j) * 16 + lr] = f2bf(v);
        }
      }
  }
  __syncthreads();   // H1 visible; stage-1 Bs reads done

  // ---------------- stage 2: h1 @ W2 ----------------
  f32x4 acc2[FM2][FC2];
#pragma unroll
  for (int i = 0; i < FM2; ++i)
#pragma unroll
    for (int j = 0; j < FC2; ++j) acc2[i][j] = (f32x4){0.f, 0.f, 0.f, 0.f};

  for (int ks = 0; ks < NKS2; ++ks) {
    const int k0 = ks * 32;
    for (int idx = tid; idx < C2 * 4; idx += 256) {
      int c = idx >> 2, chk = idx & 3;
      *(uint4*)&Bs[c * RB + chk * 8] = *(const uint4*)&Wt2[(size_t)c * C1 + k0 + chk * 8];
    }
    __syncthreads();

    short8 af[FM2], bfr[FC2];
#pragma unroll
    for (int i = 0; i < FM2; ++i) {
      int r = (wm2 * FM2 + i) * 16 + lr;
      af[i] = __builtin_bit_cast(short8, *(const uint4*)&H1[r * P1 + k0 + kg * 8]);
    }
#pragma unroll
    for (int j = 0; j < FC2; ++j) {
      int c = (wc2 * FC2 + j) * 16 + lr;
      bfr[j] = __builtin_bit_cast(short8, *(const uint4*)&Bs[c * RB + kg * 8]);
    }
#pragma unroll
    for (int i = 0; i < FM2; ++i)
#pragma unroll
      for (int j = 0; j < FC2; ++j)
        acc2[i][j] = __builtin_amdgcn_mfma_f32_16x16x32_bf16(af[i], bfr[j], acc2[i][j], 0, 0, 0);
    __syncthreads();
  }

  // ---------------- epilogue: bias + ACT2 + stats, LDS-repack, coalesced store
  float psum[FC2], psq[FC2], bl2[FC2];
#pragma unroll
  for (int j = 0; j < FC2; ++j) {
    psum[j] = 0.f; psq[j] = 0.f;
    bl2[j] = b2[(wc2 * FC2 + j) * 16 + lr];
  }
#pragma unroll
  for (int i = 0; i < FM2; ++i)
#pragma unroll
    for (int t = 0; t < 4; ++t) {
      int rl = (wm2 * FM2 + i) * 16 + kg * 4 + t;
      bool ok = (row0 + rl) < M;
#pragma unroll
      for (int j = 0; j < FC2; ++j) {
        float v = acc2[i][j][t] + bl2[j];
        if (ACT2 == 1) v = act_elu(v);
        else if (ACT2 == 2) v = tanhf(v);
        if (STATS && ok) { psum[j] += v; psq[j] += v * v; }
        H1[rl * P2 + (wc2 * FC2 + j) * 16 + lr] = f2bf(v);   // reuse H1 as copy buf
      }
    }
  __syncthreads();
  for (int idx = tid; idx < BM * (C2 / 8); idx += 256) {
    int r = idx / (C2 / 8), cc = idx % (C2 / 8);
    int row = row0 + r;
    if (row < M)
      *(uint4*)&out[(size_t)row * C2 + cc * 8] = *(const uint4*)&H1[r * P2 + cc * 8];
  }

  if (STATS) {
    for (int i = tid; i < 2 * C2; i += 256) ((float*)red)[i] = 0.f;
    __syncthreads();
#pragma unroll
    for (int j = 0; j < FC2; ++j) {
      int c = (wc2 * FC2 + j) * 16 + lr;
      atomicAdd(&red[0][c], psum[j]);
      atomicAdd(&red[1][c], psq[j]);
    }
    __syncthreads();
    for (int i = tid; i < C2; i += 256) {
      atomicAdd(&stat[i], red[0][i]);
      atomicAdd(&stat[C2 + i], red[1][i]);
    }
  }
}

// ---------------------------------------------------------------------------
// Single-layer MFMA GEMM (decoder layer 1): out = tanh(X @ W + b), MODE 0.
template<int K, int C, int BM, int NWM, int NWC, int ACT>
__global__ __launch_bounds__(256) void mgemm_k(
    const unsigned short* __restrict__ A,
    const unsigned short* __restrict__ Wt, const float* __restrict__ bias,
    unsigned short* __restrict__ out, int M)
{
  constexpr int FM = BM / (16 * NWM);
  constexpr int FC = C / (16 * NWC);
  constexpr int NKS = (K + 31) / 32;
  constexpr int RB = 40;
  constexpr int P2 = C + 8;
  static_assert(NWM * NWC == 4, "4 waves");

  __shared__ unsigned short As[BM * RB];
  __shared__ unsigned short Bs[C * RB];
  __shared__ unsigned short Ob[BM * P2];

  const int tid = threadIdx.x;
  const int row0 = blockIdx.x * BM;
  const int wave = tid >> 6, lane = tid & 63;
  const int wm = wave % NWM, wc = wave / NWM;
  const int lr = lane & 15, kg = lane >> 4;

  f32x4 acc[FM][FC];
#pragma unroll
  for (int i = 0; i < FM; ++i)
#pragma unroll
    for (int j = 0; j < FC; ++j) acc[i][j] = (f32x4){0.f, 0.f, 0.f, 0.f};

  for (int ks = 0; ks < NKS; ++ks) {
    const int k0 = ks * 32;
    for (int idx = tid; idx < (BM + C) * 4; idx += 256) {
      uint4 v = make_uint4(0, 0, 0, 0);
      if (idx < BM * 4) {
        int m = idx >> 2, chk = idx & 3;
        int kglob = k0 + chk * 8;
        int row = row0 + m;
        if (row < M && kglob + 8 <= K) v = *(const uint4*)(A + (size_t)row * K + kglob);
        *(uint4*)&As[m * RB + chk * 8] = v;
      } else {
        int i2 = idx - BM * 4;
        int c = i2 >> 2, chk = i2 & 3;
        int kglob = k0 + chk * 8;
        if (kglob + 8 <= K) v = *(const uint4*)&Wt[(size_t)c * K + kglob];
        *(uint4*)&Bs[c * RB + chk * 8] = v;
      }
    }
    __syncthreads();

    short8 af[FM], bfr[FC];
#pragma unroll
    for (int i = 0; i < FM; ++i) {
      int r = (wm * FM + i) * 16 + lr;
      af[i] = __builtin_bit_cast(short8, *(const uint4*)&As[r * RB + kg * 8]);
    }
#pragma unroll
    for (int j = 0; j < FC; ++j) {
      int c = (wc * FC + j) * 16 + lr;
      bfr[j] = __builtin_bit_cast(short8, *(const uint4*)&Bs[c * RB + kg * 8]);
    }
#pragma unroll
    for (int i = 0; i < FM; ++i)
#pragma unroll
      for (int j = 0; j < FC; ++j)
        acc[i][j] = __builtin_amdgcn_mfma_f32_16x16x32_bf16(af[i], bfr[j], acc[i][j], 0, 0, 0);
    __syncthreads();
  }

  float bl[FC];
#pragma unroll
  for (int j = 0; j < FC; ++j) bl[j] = bias[(wc * FC + j) * 16 + lr];
#pragma unroll
  for (int i = 0; i < FM; ++i)
#pragma unroll
    for (int t = 0; t < 4; ++t) {
      int rl = (wm * FM + i) * 16 + kg * 4 + t;
#pragma unroll
      for (int j = 0; j < FC; ++j) {
        float v = acc[i][j][t] + bl[j];
        if (ACT == 1) v = act_elu(v);
        else if (ACT == 2) v = tanhf(v);
        Ob[rl * P2 + (wc * FC + j) * 16 + lr] = f2bf(v);
      }
    }
  __syncthreads();
  for (int idx = tid; idx < BM * (C / 8); idx += 256) {
    int r = idx / (C / 8), cc = idx % (C / 8);
    int row = row0 + r;
    if (row < M)
      *(uint4*)&out[(size_t)row * C + cc * 8] = *(const uint4*)&Ob[r * P2 + cc * 8];
  }
}

// All weight transposes (f32 (K,C) -> bf16 (C,K), zero-pad beyond KS) in one kernel.
__global__ __launch_bounds__(256) void wtrans_all_k(
    const float* __restrict__ enW1, const float* __restrict__ enW2,
    const float* __restrict__ geW1, const float* __restrict__ geW2,
    const float* __restrict__ gnW1, const float* __restrict__ gnW2,
    const float* __restrict__ dW1,  const float* __restrict__ eeW1,
    const float* __restrict__ eeW2,
    unsigned short* __restrict__ enW1t, unsigned short* __restrict__ enW2t,
    unsigned short* __restrict__ geW1t, unsigned short* __restrict__ geW2t,
    unsigned short* __restrict__ gnW1t, unsigned short* __restrict__ gnW2t,
    unsigned short* __restrict__ dW1t,  unsigned short* __restrict__ eeW1t,
    unsigned short* __restrict__ eeW2t)
{
  int i = blockIdx.x * 256 + threadIdx.x;
#define SEG(Wsrc, Wdst, KK, CC, KS) \
  { int n = (KK) * (CC); \
    if (i < n) { int c = i / (KK), k = i - c * (KK); \
      Wdst[i] = (k < (KS)) ? f2bf(Wsrc[(size_t)k * (CC) + c]) : (unsigned short)0; return; } \
    i -= n; }
  SEG(enW1, enW1t, 40, 128, 40)
  SEG(enW2, enW2t, 128, 128, 128)
  SEG(geW1, geW1t, 288, 128, 288)
  SEG(geW2, geW2t, 128, 32, 128)
  SEG(gnW1, gnW1t, 160, 256, 160)
  SEG(gnW2, gnW2t, 256, 128, 256)
  SEG(dW1,  dW1t,  128, 128, 128)
  SEG(eeW1, eeW1t, 32, 32, 6)
  SEG(eeW2, eeW2t, 32, 32, 32)
#undef SEG
}
constexpr int WT_TOTAL = 40*128 + 128*128 + 288*128 + 128*32 + 160*256 + 256*128 + 128*128 + 32*32 + 32*32;

// out(f32) = h(bf16)*scl + shf (+ out if RES); writes bf16 mirror. BN finalize folded.
template<int C, bool RES>
__global__ __launch_bounds__(256) void normb_k(const unsigned short* __restrict__ h,
    const float* __restrict__ stat, float invM,
    const float* __restrict__ g, const float* __restrict__ be,
    float* __restrict__ out, unsigned short* __restrict__ out_bf, int total8)
{
  __shared__ float s_scl[C], s_shf[C];
  for (int i = threadIdx.x; i < C; i += 256) {
    float mu = stat[i] * invM;
    float var = stat[C + i] * invM - mu * mu;
    float s = rsqrtf(var + 1e-5f) * g[i];
    s_scl[i] = s; s_shf[i] = be[i] - mu * s;
  }
  __syncthreads();
  int i = blockIdx.x * 256 + threadIdx.x;
  if (i >= total8) return;
  int c8 = (i % (C / 8)) * 8;
  uint4 hv = ((const uint4*)h)[i];
  const unsigned short* hp = (const unsigned short*)&hv;
  float f[8];
#pragma unroll
  for (int j = 0; j < 8; ++j) f[j] = fmaf(bf2f(hp[j]), s_scl[c8 + j], s_shf[c8 + j]);
  if (RES) {
    float4 p0 = ((const float4*)out)[2 * i], p1 = ((const float4*)out)[2 * i + 1];
    f[0] += p0.x; f[1] += p0.y; f[2] += p0.z; f[3] += p0.w;
    f[4] += p1.x; f[5] += p1.y; f[6] += p1.z; f[7] += p1.w;
  }
  ((float4*)out)[2 * i]     = make_float4(f[0], f[1], f[2], f[3]);
  ((float4*)out)[2 * i + 1] = make_float4(f[4], f[5], f[6], f[7]);
  uint4 o;
  unsigned short* op = (unsigned short*)&o;
#pragma unroll
  for (int j = 0; j < 8; ++j) op[j] = f2bf(f[j]);
  ((uint4*)out_bf)[i] = o;
}

// ---- CSR build ----
__global__ __launch_bounds__(256) void csr_count_k(const int* __restrict__ ep,
    int* __restrict__ deg, int E)
{
  int e = blockIdx.x * 256 + threadIdx.x;
  if (e < E) { atomicAdd(&deg[ep[2 * e]], 1); atomicAdd(&deg[ep[2 * e + 1]], 1); }
}

__global__ __launch_bounds__(1024) void csr_scan_k(const int* __restrict__ deg,
    int* __restrict__ off, int* __restrict__ cursor, int N)
{
  __shared__ int part[1024];
  int t = threadIdx.x;
  const int CHK = (N + 1023) / 1024;
  int c0 = t * CHK, c1 = min(c0 + CHK, N);
  int s = 0;
  for (int i = c0; i < c1; ++i) s += deg[i];
  part[t] = s;
  __syncthreads();
  for (int o = 1; o < 1024; o <<= 1) {
    int v = (t >= o) ? part[t - o] : 0;
    __syncthreads();
    part[t] += v;
    __syncthreads();
  }
  int run = t ? part[t - 1] : 0;
  for (int i = c0; i < c1; ++i) { int d = deg[i]; off[i] = run; cursor[i] = run; run += d; }
}

__global__ __launch_bounds__(256) void csr_fill_k(const int* __restrict__ ep,
    int* __restrict__ cursor, int* __restrict__ eidx, int E)
{
  int e = blockIdx.x * 256 + threadIdx.x;
  if (e < E) {
    int p0 = atomicAdd(&cursor[ep[2 * e]], 1); eidx[p0] = e;
    int p1 = atomicAdd(&cursor[ep[2 * e + 1]], 1); eidx[p1] = e;
  }
}

// agg_bf[n][c] = scl[c]*sum_e h2e[e][c] + deg[n]*shf[c]  (one wave/node, finalize folded)
__global__ __launch_bounds__(256) void gather_agg_k(const unsigned short* __restrict__ h2e,
    const float* __restrict__ stat, float invM,
    const float* __restrict__ g, const float* __restrict__ be,
    const int* __restrict__ off, const int* __restrict__ deg, const int* __restrict__ eidx,
    unsigned short* __restrict__ agg_bf, int N)
{
  __shared__ float s_scl[32], s_shf[32];
  if (threadIdx.x < 32) {
    int c = threadIdx.x;
    float mu = stat[c] * invM;
    float var = stat[32 + c] * invM - mu * mu;
    float s = rsqrtf(var + 1e-5f) * g[c];
    s_scl[c] = s; s_shf[c] = be[c] - mu * s;
  }
  __syncthreads();
  int wid = (blockIdx.x * 256 + threadIdx.x) >> 6;
  if (wid >= N) return;
  int lane = threadIdx.x & 63;
  int c = lane & 31, half = lane >> 5;
  int o = off[wid], d = deg[wid];
  float s = 0.f;
  for (int i = half; i < d; i += 2) {
    int e = eidx[o + i];
    s += bf2f(h2e[(size_t)e * 32 + c]);
  }
  s += __shfl_down(s, 32, 64);
  if (half == 0) {
    float v = fmaf(s_scl[c], s, (float)d * s_shf[c]);
    agg_bf[(size_t)wid * 32 + c] = f2bf(v);
  }
}

// le(f32) += h2e*scl+shf ; refresh le bf16 mirror (finalize folded)
__global__ __launch_bounds__(256) void le_upd_k(const unsigned short* __restrict__ h2e,
    const float* __restrict__ stat, float invM,
    const float* __restrict__ g, const float* __restrict__ be,
    float* __restrict__ le, unsigned short* __restrict__ le_bf, int total8)
{
  __shared__ float s_scl[32], s_shf[32];
  if (threadIdx.x < 32) {
    int c = threadIdx.x;
    float mu = stat[c] * invM;
    float var = stat[32 + c] * invM - mu * mu;
    float s = rsqrtf(var + 1e-5f) * g[c];
    s_scl[c] = s; s_shf[c] = be[c] - mu * s;
  }
  __syncthreads();
  int i = blockIdx.x * 256 + threadIdx.x;
  if (i >= total8) return;
  int c8 = (i & 3) * 8;
  uint4 hv = ((const uint4*)h2e)[i];
  const unsigned short* hp = (const unsigned short*)&hv;
  float4 l0 = ((const float4*)le)[2 * i], l1 = ((const float4*)le)[2 * i + 1];
  float f[8] = {l0.x, l0.y, l0.z, l0.w, l1.x, l1.y, l1.z, l1.w};
#pragma unroll
  for (int j = 0; j < 8; ++j) f[j] += fmaf(bf2f(hp[j]), s_scl[c8 + j], s_shf[c8 + j]);
  ((float4*)le)[2 * i]     = make_float4(f[0], f[1], f[2], f[3]);
  ((float4*)le)[2 * i + 1] = make_float4(f[4], f[5], f[6], f[7]);
  uint4 o;
  unsigned short* op = (unsigned short*)&o;
#pragma unroll
  for (int j = 0; j < 8; ++j) op[j] = f2bf(f[j]);
  ((uint4*)le_bf)[i] = o;
}

// decoder layer2 (128->2, bf16 in) + integrate + preds
__global__ __launch_bounds__(256) void dec2i_k(const unsigned short* __restrict__ T,
    const float* __restrict__ W2, const float* __restrict__ b2,
    float* __restrict__ pos, float* __restrict__ vel, float* __restrict__ preds, int M)
{
  __shared__ float Wl[256];
  Wl[threadIdx.x] = W2[threadIdx.x];
  __syncthreads();
  int row = blockIdx.x * 256 + threadIdx.x;
  if (row >= M) return;
  float ax = b2[0], ay = b2[1];
  const uint4* t4 = (const uint4*)(T + (size_t)row * 128);
#pragma unroll
  for (int k8 = 0; k8 < 16; ++k8) {
    uint4 v = t4[k8];
    const unsigned short* p = (const unsigned short*)&v;
#pragma unroll
    for (int j = 0; j < 8; ++j) {
      float f = bf2f(p[j]);
      int k = k8 * 8 + j;
      ax = fmaf(f, Wl[2 * k], ax);
      ay = fmaf(f, Wl[2 * k + 1], ay);
    }
  }
  float2 p = ((float2*)pos)[row], vv = ((float2*)vel)[row];
  p.x += ax; p.y += ay; vv.x += ax; vv.y += ay;
  ((float2*)pos)[row] = p; ((float2*)vel)[row] = vv;
  ((float2*)preds)[row] = p;
}

// edge_feat channels 4,5 = |pos[s0]-pos[s1]| (bf16, packed u32 store)
__global__ __launch_bounds__(256) void pd_upd_k(const float* __restrict__ pos,
    const int* __restrict__ ep, unsigned short* __restrict__ efb, int E)
{
  int e = blockIdx.x * 256 + threadIdx.x;
  if (e >= E) return;
  float2 p0 = ((const float2*)pos)[ep[2 * e]];
  float2 p1 = ((const float2*)pos)[ep[2 * e + 1]];
  unsigned u = (unsigned)f2bf(fabsf(p0.x - p1.x)) | ((unsigned)f2bf(fabsf(p0.y - p1.y)) << 16);
  *(unsigned*)&efb[(size_t)e * 8 + 4] = u;
}

__global__ __launch_bounds__(256) void hist_shift_k(float* __restrict__ hist,
    unsigned short* __restrict__ histb,
    const float* __restrict__ pos, const float* __restrict__ vel, int M)
{
  int n = blockIdx.x * 256 + threadIdx.x;
  if (n >= M) return;
  float4* h4 = (float4*)(hist + (size_t)n * 40);
  float4 tmp[10];
#pragma unroll
  for (int t = 0; t < 10; ++t) tmp[t] = h4[t];
  float2 pp = ((const float2*)pos)[n], vv = ((const float2*)vel)[n];
  unsigned* hb = (unsigned*)(histb + (size_t)n * 40);
#pragma unroll
  for (int t = 0; t < 9; ++t) {
    float4 v = tmp[t + 1];
    h4[t] = v;
    hb[2 * t]     = (unsigned)f2bf(v.x) | ((unsigned)f2bf(v.y) << 16);
    hb[2 * t + 1] = (unsigned)f2bf(v.z) | ((unsigned)f2bf(v.w) << 16);
  }
  float4 nv = make_float4(pp.x, pp.y, vv.x, vv.y);
  h4[9] = nv;
  hb[18] = (unsigned)f2bf(nv.x) | ((unsigned)f2bf(nv.y) << 16);
  hb[19] = (unsigned)f2bf(nv.z) | ((unsigned)f2bf(nv.w) << 16);
}

__global__ __launch_bounds__(256) void init_nodes_k(const float4* __restrict__ nodes4,
    float* __restrict__ hist, unsigned short* __restrict__ histb,
    float* __restrict__ pos, float* __restrict__ vel,
    float* __restrict__ outGt, int M)
{
  int n = blockIdx.x * 256 + threadIdx.x;
  if (n >= M) return;
  float4* h4 = (float4*)(hist + (size_t)n * 40);
  unsigned* hb = (unsigned*)(histb + (size_t)n * 40);
  float4 v;
#pragma unroll
  for (int t = 0; t < 10; ++t) {
    v = nodes4[(size_t)t * M + n];
    h4[t] = v;
    hb[2 * t]     = (unsigned)f2bf(v.x) | ((unsigned)f2bf(v.y) << 16);
    hb[2 * t + 1] = (unsigned)f2bf(v.z) | ((unsigned)f2bf(v.w) << 16);
  }
  ((float2*)pos)[n] = make_float2(v.x, v.y);
  ((float2*)vel)[n] = make_float2(v.z, v.w);
  float4 g0 = nodes4[(size_t)10 * M + n];
  float4 g1 = nodes4[(size_t)11 * M + n];
  float2* gt2 = (float2*)outGt;
  gt2[(size_t)2 * n + 0] = make_float2(g0.x, g0.y);
  gt2[(size_t)2 * n + 1] = make_float2(g0.z, g0.w);
  gt2[(size_t)2 * (M + n) + 0] = make_float2(g1.x, g1.y);
  gt2[(size_t)2 * (M + n) + 1] = make_float2(g1.z, g1.w);
}

// edge_feat init as bf16 (E,8): [attr0, attr1, pd0 x4, 0, 0]
__global__ __launch_bounds__(256) void init_edges_k(const float4* __restrict__ nodes4,
    const float* __restrict__ attr, const int* __restrict__ ep,
    unsigned short* __restrict__ efb, int E)
{
  int e = blockIdx.x * 256 + threadIdx.x;
  if (e >= E) return;
  float4 w0 = nodes4[(size_t)10 * NN + ep[2 * e]];
  float4 w1 = nodes4[(size_t)10 * NN + ep[2 * e + 1]];
  float2 a = ((const float2*)attr)[e];
  uint4 o;
  o.x = (unsigned)f2bf(a.x) | ((unsigned)f2bf(a.y) << 16);
  o.y = (unsigned)f2bf(fabsf(w0.x - w1.x)) | ((unsigned)f2bf(fabsf(w0.y - w1.y)) << 16);
  o.z = (unsigned)f2bf(fabsf(w0.z - w1.z)) | ((unsigned)f2bf(fabsf(w0.w - w1.w)) << 16);
  o.w = 0;
  ((uint4*)efb)[e] = o;
}

__global__ __launch_bounds__(256) void loss_k(const float* __restrict__ preds,
    const float* __restrict__ gtf, float* __restrict__ acc)
{
  int i = blockIdx.x * 256 + threadIdx.x;
  float d2 = 0.f;
  if (i < 2 * NN * 2) {
    int r = i / (NN * 2);
    int rem = i - r * (NN * 2);
    int n = rem >> 1, c = rem & 1;
    float df = preds[i] - gtf[((size_t)r * NN + n) * 4 + c];
    d2 = df * df;
  }
#pragma unroll
  for (int o = 32; o > 0; o >>= 1) d2 += __shfl_down(d2, o, 64);
  __shared__ float sb[4];
  int lane = threadIdx.x & 63, w = threadIdx.x >> 6;
  if (lane == 0) sb[w] = d2;
  __syncthreads();
  if (threadIdx.x == 0) atomicAdd(acc, sb[0] + sb[1] + sb[2] + sb[3]);
}

__global__ void loss_write_k(const float* __restrict__ acc, float* __restrict__ o)
{
  float s = *acc;
  o[0] = s * 0.25f;
  o[1] = s * (1.f / 80000.f);
}

extern "C" void kernel_launch(void* const* d_in, const int* in_sizes, int n_in,
                              void* d_out, int out_size, void* d_ws, size_t ws_size,
                              hipStream_t stream)
{
  (void)in_sizes; (void)n_in; (void)out_size; (void)ws_size;
  const float* nodes = (const float*)d_in[0];
  const int*   ep    = (const int*)d_in[1];
  const float* eattr = (const float*)d_in[2];
  const float *en_W1 = (const float*)d_in[3],  *en_b1 = (const float*)d_in[4],
              *en_W2 = (const float*)d_in[5],  *en_b2 = (const float*)d_in[6],
              *en_g  = (const float*)d_in[7],  *en_be = (const float*)d_in[8];
  const float *ee_W1 = (const float*)d_in[9],  *ee_b1 = (const float*)d_in[10],
              *ee_W2 = (const float*)d_in[11], *ee_b2 = (const float*)d_in[12],
              *ee_g  = (const float*)d_in[13], *ee_be = (const float*)d_in[14];
  const float *ge_W1 = (const float*)d_in[15], *ge_b1 = (const float*)d_in[16],
              *ge_W2 = (const float*)d_in[17], *ge_b2 = (const float*)d_in[18],
              *ge_g  = (const float*)d_in[19], *ge_be = (const float*)d_in[20];
  const float *gn_W1 = (const float*)d_in[21], *gn_b1 = (const float*)d_in[22],
              *gn_W2 = (const float*)d_in[23], *gn_b2 = (const float*)d_in[24],
              *gn_g  = (const float*)d_in[25], *gn_be = (const float*)d_in[26];
  const float *d_W1  = (const float*)d_in[27], *d_b1  = (const float*)d_in[28],
              *d_W2  = (const float*)d_in[29], *d_b2  = (const float*)d_in[30];

  float* out = (float*)d_out;
  float* outPreds = out;
  float* outLoss  = out + 80000;
  float* outGt    = out + 80002;

  float* ws = (float*)d_ws;
  size_t off = 0;
  auto alloc = [&](size_t nf) { float* p = ws + off; off += (nf + 15) & ~(size_t)15; return p; };
  float* hist  = alloc((size_t)NN * 40);
  unsigned short* histb = (unsigned short*)alloc((size_t)NN * 20);
  unsigned short* efb   = (unsigned short*)alloc((size_t)NE * 4);    // (E,8) bf16
  float* ln    = alloc((size_t)NN * 128);
  unsigned short* lnb  = (unsigned short*)alloc((size_t)NN * 64);
  float* le    = alloc((size_t)NE * 32);
  unsigned short* leb  = (unsigned short*)alloc((size_t)NE * 16);
  unsigned short* e32b = (unsigned short*)alloc((size_t)NE * 16);    // ee / ge output (E,32) bf16
  unsigned short* h2nb = (unsigned short*)alloc((size_t)NN * 64);    // node MLP out (N,128) bf16
  unsigned short* dtb  = (unsigned short*)alloc((size_t)NN * 64);    // decoder tanh out (N,128) bf16
  unsigned short* aggb = (unsigned short*)alloc((size_t)NN * 16);    // (N,32) bf16
  float* pos   = alloc((size_t)NN * 2);
  float* vel   = alloc((size_t)NN * 2);
  unsigned short* enW1t = (unsigned short*)alloc(40 * 128 / 2);
  unsigned short* enW2t = (unsigned short*)alloc(128 * 128 / 2);
  unsigned short* geW1t = (unsigned short*)alloc(288 * 128 / 2);
  unsigned short* geW2t = (unsigned short*)alloc(128 * 32 / 2);
  unsigned short* gnW1t = (unsigned short*)alloc(160 * 256 / 2);
  unsigned short* gnW2t = (unsigned short*)alloc(256 * 128 / 2);
  unsigned short* dW1t  = (unsigned short*)alloc(128 * 128 / 2);
  unsigned short* eeW1t = (unsigned short*)alloc(32 * 32 / 2);
  unsigned short* eeW2t = (unsigned short*)alloc(32 * 32 / 2);
  float* statArr = alloc(12 * 256 + 16);     // 12 BN-stat slots + loss acc
  float* lacc    = statArr + 12 * 256;
  int* deg    = (int*)alloc(NN);
  int* coff   = (int*)alloc(NN);
  int* cursor = (int*)alloc(NN);
  int* eidx   = (int*)alloc(2 * (size_t)NE);

  hipMemsetAsync(statArr, 0, (12 * 256 + 16) * sizeof(float), stream);
  hipMemsetAsync(deg, 0, NN * sizeof(int), stream);

  wtrans_all_k<<<(WT_TOTAL + 255) / 256, 256, 0, stream>>>(
      en_W1, en_W2, ge_W1, ge_W2, gn_W1, gn_W2, d_W1, ee_W1, ee_W2,
      enW1t, enW2t, geW1t, geW2t, gnW1t, gnW2t, dW1t, eeW1t, eeW2t);

  init_nodes_k<<<(NN + 255) / 256, 256, 0, stream>>>((const float4*)nodes, hist, histb, pos, vel, outGt, NN);
  init_edges_k<<<(NE + 255) / 256, 256, 0, stream>>>((const float4*)nodes, eattr, ep, efb, NE);

  csr_count_k<<<(NE + 255) / 256, 256, 0, stream>>>(ep, deg, NE);
  csr_scan_k<<<1, 1024, 0, stream>>>(deg, coff, cursor, NN);
  csr_fill_k<<<(NE + 255) / 256, 256, 0, stream>>>(ep, cursor, eidx, NE);

  const int GN  = (NN + 63) / 64;           // 313: node MLPs, BM=64
  const int GE  = NE / 128;                 // 2500: edge MLPs, BM=128
  const int G_N8 = (NN * 16 + 255) / 256;   // normb C=128 over N
  const int G_E8 = (NE * 4 + 255) / 256;    // normb C=32 over E / le_upd

  for (int r = 0; r < 2; ++r) {
    float* sEN = statArr + (r * 6 + 0) * 256;
    float* sEE = statArr + (r * 6 + 1) * 256;

    // ---- node encoder (fused 2-layer) ----
    mlp2_k<40, 128, 128, 64, 2, 2, 2, 2, 1, true, 0><<<GN, 256, 0, stream>>>(
        histb, nullptr, nullptr, enW1t, en_b1, enW2t, en_b2, h2nb, NN, sEN);
    normb_k<128, false><<<G_N8, 256, 0, stream>>>(h2nb, sEN, 1.f / NN, en_g, en_be, ln, lnb, NN * 16);

    // ---- edge encoder (fused 2-layer, K zero-padded to 32) ----
    mlp2_k<32, 32, 32, 128, 4, 1, 4, 1, 1, true, 3><<<GE, 256, 0, stream>>>(
        efb, nullptr, nullptr, eeW1t, ee_b1, eeW2t, ee_b2, e32b, NE, sEE);
    normb_k<32, false><<<G_E8, 256, 0, stream>>>(e32b, sEE, 1.f / NE, ee_g, ee_be, le, leb, NE * 4);

    for (int mp = 0; mp < 2; ++mp) {
      float* sGE = statArr + (r * 6 + 2 + mp * 2) * 256;
      float* sGN = statArr + (r * 6 + 3 + mp * 2) * 256;

      // ---- ge MLP (fused 2-layer, gather staged in-kernel, full E) ----
      mlp2_k<288, 128, 32, 128, 2, 2, 4, 1, 1, true, 1><<<GE, 256, 0, stream>>>(
          lnb, leb, ep, geW1t, ge_b1, geW2t, ge_b2, e32b, NE, sGE);

      // ---- aggregation (CSR gather) + le update (BN finalize folded) ----
      gather_agg_k<<<(NN * 64 + 255) / 256, 256, 0, stream>>>(e32b, sGE, 1.f / NE, ge_g, ge_be, coff, deg, eidx, aggb, NN);
      le_upd_k<<<G_E8, 256, 0, stream>>>(e32b, sGE, 1.f / NE, ge_g, ge_be, le, leb, NE * 4);

      // ---- gn MLP (fused 2-layer) + residual ----
      mlp2_k<160, 256, 128, 64, 2, 2, 2, 2, 1, true, 2><<<GN, 256, 0, stream>>>(
          lnb, aggb, nullptr, gnW1t, gn_b1, gnW2t, gn_b2, h2nb, NN, sGN);
      normb_k<128, true><<<G_N8, 256, 0, stream>>>(h2nb, sGN, 1.f / NN, gn_g, gn_be, ln, lnb, NN * 16);
    }

    // ---- decoder + integrate ----
    mgemm_k<128, 128, 64, 2, 2, 2><<<GN, 256, 0, stream>>>(lnb, dW1t, d_b1, dtb, NN);
    dec2i_k<<<(NN + 255) / 256, 256, 0, stream>>>(dtb, d_W2, d_b2, pos, vel, outPreds + (size_t)r * NN * 2, NN);

    if (r == 0) {
      pd_upd_k<<<(NE + 255) / 256, 256, 0, stream>>>(pos, ep, efb, NE);
      hist_shift_k<<<(NN + 255) / 256, 256, 0, stream>>>(hist, histb, pos, vel, NN);
    }
  }

  loss_k<<<(2 * NN * 2 + 255) / 256, 256, 0, stream>>>(outPreds, outGt, lacc);
  loss_write_k<<<1, 1, 0, stream>>>(lacc, outLoss);
}